// Round 1
// baseline (733.377 us; speedup 1.0000x reference)
//
#include <hip/hip_runtime.h>
#include <hip/hip_bf16.h>
#include <math.h>

#define NH 4
#define DK 32
#define CC 128
#define HW 56
#define SHIFT 3
#define NTOK 12544   // 4*56*56 == 256*49
#define S_GLB 3136
#define NWIN 256

// ---------------- Kernel 1: shift + window-partition gather + QKV projection
__global__ __launch_bounds__(128) void win_qkv_k(
    const float* __restrict__ x,
    const float* __restrict__ wq, const float* __restrict__ bq,
    const float* __restrict__ wk, const float* __restrict__ bk,
    const float* __restrict__ wv, const float* __restrict__ bv,
    float* __restrict__ q, float* __restrict__ k, float* __restrict__ v) {
  __shared__ float xs[8][CC];
  const int t0 = blockIdx.x * 8;
  const int tid = threadIdx.x;
  for (int t2 = 0; t2 < 8; ++t2) {
    const int t = t0 + t2;
    const int win = t / 49, tok = t % 49;
    const int b = win >> 6, wrem = win & 63;
    const int wi = wrem >> 3, wj = wrem & 7;
    const int i = tok / 7, j = tok % 7;
    int hh = wi * 7 + i + SHIFT; if (hh >= HW) hh -= HW;
    int ww = wj * 7 + j + SHIFT; if (ww >= HW) ww -= HW;
    xs[t2][tid] = x[((b * HW + hh) * HW + ww) * CC + tid];
  }
  __syncthreads();
  float aq[8], ak[8], av[8];
  {
    const float bqv = bq[tid], bkv = bk[tid], bvv = bv[tid];
    for (int t2 = 0; t2 < 8; ++t2) { aq[t2] = bqv; ak[t2] = bkv; av[t2] = bvv; }
  }
#pragma unroll 4
  for (int i2 = 0; i2 < CC; ++i2) {
    const float wqv = wq[i2 * CC + tid];
    const float wkv = wk[i2 * CC + tid];
    const float wvv = wv[i2 * CC + tid];
#pragma unroll
    for (int t2 = 0; t2 < 8; ++t2) {
      const float xv = xs[t2][i2];
      aq[t2] = fmaf(xv, wqv, aq[t2]);
      ak[t2] = fmaf(xv, wkv, ak[t2]);
      av[t2] = fmaf(xv, wvv, av[t2]);
    }
  }
  const int head = tid >> 5, d = tid & 31;
  for (int t2 = 0; t2 < 8; ++t2) {
    const int t = t0 + t2;
    const int win = t / 49, tok = t % 49;
    const int o = ((win * NH + head) * 49 + tok) * DK + d;
    q[o] = aq[t2]; k[o] = ak[t2]; v[o] = av[t2];
  }
}

// ---------------- Kernel 2: per-(window,head) attention, s=49
__global__ __launch_bounds__(256) void win_attn_k(
    const float* __restrict__ q, const float* __restrict__ k,
    const float* __restrict__ v, float* __restrict__ ao) {
  __shared__ float qs[49][33], ks[49][33], vs[49][33];
  __shared__ float ss[49][49];
  __shared__ float rinv[49];
  const int wh = blockIdx.x;   // win*4 + head
  const int tid = threadIdx.x;
  const float* qg = q + wh * 49 * DK;
  const float* kg = k + wh * 49 * DK;
  const float* vg = v + wh * 49 * DK;
  for (int e = tid; e < 49 * DK; e += 256) {
    const int r = e >> 5, d = e & 31;
    qs[r][d] = qg[e]; ks[r][d] = kg[e]; vs[r][d] = vg[e];
  }
  __syncthreads();
  const float scale = 0.17677669529663687f;  // 1/sqrt(32)
  for (int e = tid; e < 49 * 49; e += 256) {
    const int qi = e / 49, ki = e % 49;
    float s = 0.f;
#pragma unroll
    for (int i = 0; i < DK; ++i) s = fmaf(qs[qi][i], ks[ki][i], s);
    ss[qi][ki] = s * scale;
  }
  __syncthreads();
  if (tid < 49) {
    float mx = -1e30f;
    for (int i = 0; i < 49; ++i) mx = fmaxf(mx, ss[tid][i]);
    float sum = 0.f;
    for (int i = 0; i < 49; ++i) { const float p = __expf(ss[tid][i] - mx); ss[tid][i] = p; sum += p; }
    rinv[tid] = 1.0f / sum;
  }
  __syncthreads();
  const int win = wh >> 2, head = wh & 3;
  for (int e = tid; e < 49 * DK; e += 256) {
    const int qi = e >> 5, d = e & 31;
    float o = 0.f;
#pragma unroll
    for (int i = 0; i < 49; ++i) o = fmaf(ss[qi][i], vs[i][d], o);
    ao[(win * 49 + qi) * CC + head * DK + d] = o * rinv[qi];
  }
}

// ---------------- Kernel 3: window-reverse + unshift + output projection
__global__ __launch_bounds__(128) void win_proj_k(
    const float* __restrict__ ao, const float* __restrict__ wo,
    const float* __restrict__ bo, float* __restrict__ xf) {
  __shared__ float as_[8][CC];
  const int t0 = blockIdx.x * 8;
  const int tid = threadIdx.x;
  for (int t2 = 0; t2 < 8; ++t2) {
    const int t = t0 + t2;
    const int b = t / S_GLB, rem = t % S_GLB;
    const int h = rem / HW, w = rem % HW;
    int hs = h + (HW - SHIFT); if (hs >= HW) hs -= HW;
    int wsp = w + (HW - SHIFT); if (wsp >= HW) wsp -= HW;
    const int wi = hs / 7, ii = hs % 7, wj = wsp / 7, jj = wsp % 7;
    const int win = (b << 6) + wi * 8 + wj;
    const int tok = ii * 7 + jj;
    as_[t2][tid] = ao[(win * 49 + tok) * CC + tid];
  }
  __syncthreads();
  float acc[8];
  { const float bov = bo[tid]; for (int t2 = 0; t2 < 8; ++t2) acc[t2] = bov; }
#pragma unroll 4
  for (int i2 = 0; i2 < CC; ++i2) {
    const float w_ = wo[i2 * CC + tid];
#pragma unroll
    for (int t2 = 0; t2 < 8; ++t2) acc[t2] = fmaf(as_[t2][i2], w_, acc[t2]);
  }
  for (int t2 = 0; t2 < 8; ++t2) xf[(t0 + t2) * CC + tid] = acc[t2];
}

// ---------------- Kernel 4: LN1 + QKV projection (global attention layout)
__global__ __launch_bounds__(128) void glb_ln_qkv_k(
    const float* __restrict__ xf,
    const float* __restrict__ wq, const float* __restrict__ bq,
    const float* __restrict__ wk, const float* __restrict__ bk,
    const float* __restrict__ wv, const float* __restrict__ bv,
    const float* __restrict__ g1, const float* __restrict__ be1,
    float* __restrict__ q, float* __restrict__ k, float* __restrict__ v) {
  __shared__ float xs[8][CC];
  __shared__ float ys[8][CC];
  __shared__ float red[8][2];
  const int t0 = blockIdx.x * 8;
  const int tid = threadIdx.x;
  for (int t2 = 0; t2 < 8; ++t2) xs[t2][tid] = xf[(t0 + t2) * CC + tid];
  __syncthreads();
  const int wvi = tid >> 6, lane = tid & 63;
  for (int t2 = wvi * 4; t2 < wvi * 4 + 4; ++t2) {
    const float v0 = xs[t2][lane], v1 = xs[t2][64 + lane];
    float s = v0 + v1, sq = v0 * v0 + v1 * v1;
#pragma unroll
    for (int off = 1; off < 64; off <<= 1) { s += __shfl_xor(s, off); sq += __shfl_xor(sq, off); }
    if (lane == 0) {
      const float mu = s * 0.0078125f;
      const float var = sq * 0.0078125f - mu * mu;
      red[t2][0] = mu; red[t2][1] = rsqrtf(var + 1e-5f);
    }
  }
  __syncthreads();
  {
    const float gg = g1[tid], bb = be1[tid];
    for (int t2 = 0; t2 < 8; ++t2)
      ys[t2][tid] = (xs[t2][tid] - red[t2][0]) * red[t2][1] * gg + bb;
  }
  __syncthreads();
  float aq[8], ak[8], av[8];
  {
    const float bqv = bq[tid], bkv = bk[tid], bvv = bv[tid];
    for (int t2 = 0; t2 < 8; ++t2) { aq[t2] = bqv; ak[t2] = bkv; av[t2] = bvv; }
  }
#pragma unroll 4
  for (int i2 = 0; i2 < CC; ++i2) {
    const float wqv = wq[i2 * CC + tid];
    const float wkv = wk[i2 * CC + tid];
    const float wvv = wv[i2 * CC + tid];
#pragma unroll
    for (int t2 = 0; t2 < 8; ++t2) {
      const float xv = ys[t2][i2];
      aq[t2] = fmaf(xv, wqv, aq[t2]);
      ak[t2] = fmaf(xv, wkv, ak[t2]);
      av[t2] = fmaf(xv, wvv, av[t2]);
    }
  }
  const int head = tid >> 5, d = tid & 31;
  for (int t2 = 0; t2 < 8; ++t2) {
    const int t = t0 + t2;
    const int b = t / S_GLB, s = t - b * S_GLB;
    const int o = ((b * NH + head) * S_GLB + s) * DK + d;
    q[o] = aq[t2]; k[o] = ak[t2]; v[o] = av[t2];
  }
}

// ---------------- Kernel 5: global flash attention (S=3136, dk=32)
__global__ __launch_bounds__(256) void glb_attn_k(
    const float* __restrict__ q, const float* __restrict__ k,
    const float* __restrict__ v, float* __restrict__ ao) {
  __shared__ float ks_[64][36];
  __shared__ float vs_[64][36];
  __shared__ float ps_[32][65];
  __shared__ float qs_[32][33];
  const int tid = threadIdx.x;
  const int bh = blockIdx.y;
  const int qbase = blockIdx.x * 32;
  const float* qg = q + (bh * S_GLB + qbase) * DK;
  const float* kg = k + bh * S_GLB * DK;
  const float* vg = v + bh * S_GLB * DK;
  const int tq = tid >> 3, g = tid & 7;
  for (int e = tid; e < 32 * 32; e += 256) qs_[e >> 5][e & 31] = qg[e];
  __syncthreads();
  float qr[32];
  const float scale = 0.17677669529663687f;
#pragma unroll
  for (int i = 0; i < 32; ++i) qr[i] = qs_[tq][i] * scale;
  float m = -1e30f, l = 0.f;
  float o0 = 0.f, o1 = 0.f, o2 = 0.f, o3 = 0.f;
  for (int kt = 0; kt < 49; ++kt) {
    __syncthreads();
    const float* kgt = kg + kt * 2048;
    const float* vgt = vg + kt * 2048;
    for (int e = tid; e < 2048; e += 256) {
      const int r = e >> 5, d = e & 31;
      ks_[r][d] = kgt[e];
      vs_[r][d] = vgt[e];
    }
    __syncthreads();
    float sc[8];
    float tmax = -1e30f;
#pragma unroll
    for (int jj = 0; jj < 8; ++jj) {
      const int kk = g + (jj << 3);
      float s = 0.f;
#pragma unroll
      for (int i4 = 0; i4 < 8; ++i4) {
        const float4 kv = *reinterpret_cast<const float4*>(&ks_[kk][i4 * 4]);
        s = fmaf(qr[i4 * 4 + 0], kv.x, s);
        s = fmaf(qr[i4 * 4 + 1], kv.y, s);
        s = fmaf(qr[i4 * 4 + 2], kv.z, s);
        s = fmaf(qr[i4 * 4 + 3], kv.w, s);
      }
      sc[jj] = s;
      tmax = fmaxf(tmax, s);
    }
    tmax = fmaxf(tmax, __shfl_xor(tmax, 1));
    tmax = fmaxf(tmax, __shfl_xor(tmax, 2));
    tmax = fmaxf(tmax, __shfl_xor(tmax, 4));
    const float mnew = fmaxf(m, tmax);
    const float corr = __expf(m - mnew);
    float psum = 0.f;
#pragma unroll
    for (int jj = 0; jj < 8; ++jj) {
      const float p = __expf(sc[jj] - mnew);
      ps_[tq][g + (jj << 3)] = p;
      psum += p;
    }
    psum += __shfl_xor(psum, 1);
    psum += __shfl_xor(psum, 2);
    psum += __shfl_xor(psum, 4);
    l = l * corr + psum;
    o0 *= corr; o1 *= corr; o2 *= corr; o3 *= corr;
    m = mnew;
    // ps_ row is written and read by the same 8 consecutive lanes (same wave):
    // DS ops execute in order within a wave, no barrier needed.
#pragma unroll
    for (int kk = 0; kk < 64; ++kk) {
      const float p = ps_[tq][kk];
      const float4 vv = *reinterpret_cast<const float4*>(&vs_[kk][g * 4]);
      o0 = fmaf(p, vv.x, o0);
      o1 = fmaf(p, vv.y, o1);
      o2 = fmaf(p, vv.z, o2);
      o3 = fmaf(p, vv.w, o3);
    }
  }
  const float rl = 1.0f / l;
  const int b = bh >> 2, head = bh & 3;
  const int t = b * S_GLB + qbase + tq;
  float4 o4;
  o4.x = o0 * rl; o4.y = o1 * rl; o4.z = o2 * rl; o4.w = o3 * rl;
  *reinterpret_cast<float4*>(&ao[t * CC + head * DK + g * 4]) = o4;
}

// ---------------- Kernel 6: global out-projection + residual (in-place xf)
__global__ __launch_bounds__(128) void glb_proj_k(
    const float* __restrict__ ao, const float* __restrict__ wo,
    const float* __restrict__ bo, float* __restrict__ xf) {
  __shared__ float as_[8][CC];
  const int t0 = blockIdx.x * 8;
  const int tid = threadIdx.x;
  for (int t2 = 0; t2 < 8; ++t2) as_[t2][tid] = ao[(t0 + t2) * CC + tid];
  __syncthreads();
  float acc[8];
  { const float bov = bo[tid]; for (int t2 = 0; t2 < 8; ++t2) acc[t2] = bov; }
#pragma unroll 4
  for (int i2 = 0; i2 < CC; ++i2) {
    const float w_ = wo[i2 * CC + tid];
#pragma unroll
    for (int t2 = 0; t2 < 8; ++t2) acc[t2] = fmaf(as_[t2][i2], w_, acc[t2]);
  }
  for (int t2 = 0; t2 < 8; ++t2) {
    const int idx = (t0 + t2) * CC + tid;
    xf[idx] = xf[idx] + acc[t2];
  }
}

// ---------------- Kernel 7: LN2 + FC1 + exact gelu
__global__ __launch_bounds__(512) void mlp_fc1_k(
    const float* __restrict__ xf, const float* __restrict__ w1,
    const float* __restrict__ b1, const float* __restrict__ g2,
    const float* __restrict__ be2, float* __restrict__ h) {
  __shared__ float xs[8][CC];
  __shared__ float ys[8][CC];
  __shared__ float red[8][2];
  const int t0 = blockIdx.x * 8;
  const int tid = threadIdx.x;
  for (int e = tid; e < 8 * CC; e += 512) xs[e >> 7][e & 127] = xf[t0 * CC + e];
  __syncthreads();
  const int wvi = tid >> 6, lane = tid & 63;
  {
    const int t2 = wvi;  // 8 waves -> 8 tokens
    const float v0 = xs[t2][lane], v1 = xs[t2][64 + lane];
    float s = v0 + v1, sq = v0 * v0 + v1 * v1;
#pragma unroll
    for (int off = 1; off < 64; off <<= 1) { s += __shfl_xor(s, off); sq += __shfl_xor(sq, off); }
    if (lane == 0) {
      const float mu = s * 0.0078125f;
      const float var = sq * 0.0078125f - mu * mu;
      red[t2][0] = mu; red[t2][1] = rsqrtf(var + 1e-5f);
    }
  }
  __syncthreads();
  for (int e = tid; e < 8 * CC; e += 512) {
    const int t2 = e >> 7, c = e & 127;
    ys[t2][c] = (xs[t2][c] - red[t2][0]) * red[t2][1] * g2[c] + be2[c];
  }
  __syncthreads();
  float acc[8];
  { const float bb = b1[tid]; for (int t2 = 0; t2 < 8; ++t2) acc[t2] = bb; }
#pragma unroll 4
  for (int i2 = 0; i2 < CC; ++i2) {
    const float w_ = w1[i2 * 512 + tid];
#pragma unroll
    for (int t2 = 0; t2 < 8; ++t2) acc[t2] = fmaf(ys[t2][i2], w_, acc[t2]);
  }
  for (int t2 = 0; t2 < 8; ++t2) {
    const float vph = acc[t2];
    h[(t0 + t2) * 512 + tid] = 0.5f * vph * (1.0f + erff(vph * 0.70710678118f));
  }
}

// ---------------- Kernel 8: FC2 + residual -> out
__global__ __launch_bounds__(128) void mlp_fc2_k(
    const float* __restrict__ h, const float* __restrict__ w2,
    const float* __restrict__ b2, const float* __restrict__ xf,
    float* __restrict__ out) {
  __shared__ float hs[8][512];
  const int t0 = blockIdx.x * 8;
  const int tid = threadIdx.x;
  for (int e = tid; e < 8 * 512; e += 128) hs[e >> 9][e & 511] = h[t0 * 512 + e];
  __syncthreads();
  float acc[8];
  for (int t2 = 0; t2 < 8; ++t2) acc[t2] = 0.f;
#pragma unroll 4
  for (int i2 = 0; i2 < 512; ++i2) {
    const float w_ = w2[i2 * CC + tid];
#pragma unroll
    for (int t2 = 0; t2 < 8; ++t2) acc[t2] = fmaf(hs[t2][i2], w_, acc[t2]);
  }
  const float bb = b2[tid];
  for (int t2 = 0; t2 < 8; ++t2) {
    const int idx = (t0 + t2) * CC + tid;
    out[idx] = xf[idx] + bb + acc[t2];
  }
}

extern "C" void kernel_launch(void* const* d_in, const int* in_sizes, int n_in,
                              void* d_out, int out_size, void* d_ws, size_t ws_size,
                              hipStream_t stream) {
  (void)in_sizes; (void)n_in; (void)out_size; (void)ws_size;
  const float* x   = (const float*)d_in[0];
  const float* wq  = (const float*)d_in[1];
  const float* bq  = (const float*)d_in[2];
  const float* wk  = (const float*)d_in[3];
  const float* bk  = (const float*)d_in[4];
  const float* wv  = (const float*)d_in[5];
  const float* bv  = (const float*)d_in[6];
  const float* wo  = (const float*)d_in[7];
  const float* bo  = (const float*)d_in[8];
  const float* w1  = (const float*)d_in[9];
  const float* b1  = (const float*)d_in[10];
  const float* w2  = (const float*)d_in[11];
  const float* b2  = (const float*)d_in[12];
  const float* g1  = (const float*)d_in[13];
  const float* be1 = (const float*)d_in[14];
  const float* g2  = (const float*)d_in[15];
  const float* be2 = (const float*)d_in[16];
  float* out = (float*)d_out;

  float* ws = (float*)d_ws;
  float* q  = ws;
  float* k  = q + (size_t)NTOK * CC;
  float* v  = k + (size_t)NTOK * CC;
  float* ao = v + (size_t)NTOK * CC;
  float* xf = ao + (size_t)NTOK * CC;
  float* h  = xf + (size_t)NTOK * CC;

  win_qkv_k<<<NTOK / 8, 128, 0, stream>>>(x, wq, bq, wk, bk, wv, bv, q, k, v);
  win_attn_k<<<NWIN * NH, 256, 0, stream>>>(q, k, v, ao);
  win_proj_k<<<NTOK / 8, 128, 0, stream>>>(ao, wo, bo, xf);
  glb_ln_qkv_k<<<NTOK / 8, 128, 0, stream>>>(xf, wq, bq, wk, bk, wv, bv, g1, be1, q, k, v);
  glb_attn_k<<<dim3(S_GLB / 32, 16), 256, 0, stream>>>(q, k, v, ao);
  glb_proj_k<<<NTOK / 8, 128, 0, stream>>>(ao, wo, bo, xf);
  mlp_fc1_k<<<NTOK / 8, 512, 0, stream>>>(xf, w1, b1, g2, be2, h);
  mlp_fc2_k<<<NTOK / 8, 128, 0, stream>>>(h, w2, b2, xf, out);
}

// Round 2
// 349.630 us; speedup vs baseline: 2.0976x; 2.0976x over previous
//
#include <hip/hip_runtime.h>
#include <hip/hip_bf16.h>
#include <math.h>

#define NH 4
#define DK 32
#define CC 128
#define HW 56
#define SHIFT 3
#define NTOK 12544   // 4*56*56 == 256*49
#define S_GLB 3136
#define NWIN 256

typedef unsigned short u16;
typedef short bf16x8 __attribute__((ext_vector_type(8)));   // 8 bf16 in 4 VGPRs
typedef unsigned short u16x8 __attribute__((ext_vector_type(8)));
typedef unsigned short u16x4 __attribute__((ext_vector_type(4)));
typedef float f32x4 __attribute__((ext_vector_type(4)));

static __device__ __forceinline__ u16 f2bf(float f) {
  unsigned int b = __builtin_bit_cast(unsigned int, f);
  return (u16)((b + 0x7FFFu + ((b >> 16) & 1u)) >> 16);
}

// ---------------- Kernel 1: shift + window-partition gather + QKV projection (fp32)
__global__ __launch_bounds__(128) void win_qkv_k(
    const float* __restrict__ x,
    const float* __restrict__ wq, const float* __restrict__ bq,
    const float* __restrict__ wk, const float* __restrict__ bk,
    const float* __restrict__ wv, const float* __restrict__ bv,
    float* __restrict__ q, float* __restrict__ k, float* __restrict__ v) {
  __shared__ float xs[8][CC];
  const int t0 = blockIdx.x * 8;
  const int tid = threadIdx.x;
  for (int t2 = 0; t2 < 8; ++t2) {
    const int t = t0 + t2;
    const int win = t / 49, tok = t % 49;
    const int b = win >> 6, wrem = win & 63;
    const int wi = wrem >> 3, wj = wrem & 7;
    const int i = tok / 7, j = tok % 7;
    int hh = wi * 7 + i + SHIFT; if (hh >= HW) hh -= HW;
    int ww = wj * 7 + j + SHIFT; if (ww >= HW) ww -= HW;
    xs[t2][tid] = x[((b * HW + hh) * HW + ww) * CC + tid];
  }
  __syncthreads();
  float aq[8], ak[8], av[8];
  {
    const float bqv = bq[tid], bkv = bk[tid], bvv = bv[tid];
    for (int t2 = 0; t2 < 8; ++t2) { aq[t2] = bqv; ak[t2] = bkv; av[t2] = bvv; }
  }
#pragma unroll 4
  for (int i2 = 0; i2 < CC; ++i2) {
    const float wqv = wq[i2 * CC + tid];
    const float wkv = wk[i2 * CC + tid];
    const float wvv = wv[i2 * CC + tid];
#pragma unroll
    for (int t2 = 0; t2 < 8; ++t2) {
      const float xv = xs[t2][i2];
      aq[t2] = fmaf(xv, wqv, aq[t2]);
      ak[t2] = fmaf(xv, wkv, ak[t2]);
      av[t2] = fmaf(xv, wvv, av[t2]);
    }
  }
  const int head = tid >> 5, d = tid & 31;
  for (int t2 = 0; t2 < 8; ++t2) {
    const int t = t0 + t2;
    const int win = t / 49, tok = t % 49;
    const int o = ((win * NH + head) * 49 + tok) * DK + d;
    q[o] = aq[t2]; k[o] = ak[t2]; v[o] = av[t2];
  }
}

// ---------------- Kernel 2: per-(window,head) attention, s=49 (fp32)
__global__ __launch_bounds__(256) void win_attn_k(
    const float* __restrict__ q, const float* __restrict__ k,
    const float* __restrict__ v, float* __restrict__ ao) {
  __shared__ float qs[49][33], ks[49][33], vs[49][33];
  __shared__ float ss[49][49];
  __shared__ float rinv[49];
  const int wh = blockIdx.x;
  const int tid = threadIdx.x;
  const float* qg = q + wh * 49 * DK;
  const float* kg = k + wh * 49 * DK;
  const float* vg = v + wh * 49 * DK;
  for (int e = tid; e < 49 * DK; e += 256) {
    const int r = e >> 5, d = e & 31;
    qs[r][d] = qg[e]; ks[r][d] = kg[e]; vs[r][d] = vg[e];
  }
  __syncthreads();
  const float scale = 0.17677669529663687f;
  for (int e = tid; e < 49 * 49; e += 256) {
    const int qi = e / 49, ki = e % 49;
    float s = 0.f;
#pragma unroll
    for (int i = 0; i < DK; ++i) s = fmaf(qs[qi][i], ks[ki][i], s);
    ss[qi][ki] = s * scale;
  }
  __syncthreads();
  if (tid < 49) {
    float mx = -1e30f;
    for (int i = 0; i < 49; ++i) mx = fmaxf(mx, ss[tid][i]);
    float sum = 0.f;
    for (int i = 0; i < 49; ++i) { const float p = __expf(ss[tid][i] - mx); ss[tid][i] = p; sum += p; }
    rinv[tid] = 1.0f / sum;
  }
  __syncthreads();
  const int win = wh >> 2, head = wh & 3;
  for (int e = tid; e < 49 * DK; e += 256) {
    const int qi = e >> 5, d = e & 31;
    float o = 0.f;
#pragma unroll
    for (int i = 0; i < 49; ++i) o = fmaf(ss[qi][i], vs[i][d], o);
    ao[(win * 49 + qi) * CC + head * DK + d] = o * rinv[qi];
  }
}

// ---------------- Kernel 3: window-reverse + unshift + output projection (fp32)
__global__ __launch_bounds__(128) void win_proj_k(
    const float* __restrict__ ao, const float* __restrict__ wo,
    const float* __restrict__ bo, float* __restrict__ xf) {
  __shared__ float as_[8][CC];
  const int t0 = blockIdx.x * 8;
  const int tid = threadIdx.x;
  for (int t2 = 0; t2 < 8; ++t2) {
    const int t = t0 + t2;
    const int b = t / S_GLB, rem = t % S_GLB;
    const int h = rem / HW, w = rem % HW;
    int hs = h + (HW - SHIFT); if (hs >= HW) hs -= HW;
    int wsp = w + (HW - SHIFT); if (wsp >= HW) wsp -= HW;
    const int wi = hs / 7, ii = hs % 7, wj = wsp / 7, jj = wsp % 7;
    const int win = (b << 6) + wi * 8 + wj;
    const int tok = ii * 7 + jj;
    as_[t2][tid] = ao[(win * 49 + tok) * CC + tid];
  }
  __syncthreads();
  float acc[8];
  { const float bov = bo[tid]; for (int t2 = 0; t2 < 8; ++t2) acc[t2] = bov; }
#pragma unroll 4
  for (int i2 = 0; i2 < CC; ++i2) {
    const float w_ = wo[i2 * CC + tid];
#pragma unroll
    for (int t2 = 0; t2 < 8; ++t2) acc[t2] = fmaf(as_[t2][i2], w_, acc[t2]);
  }
  for (int t2 = 0; t2 < 8; ++t2) xf[(t0 + t2) * CC + tid] = acc[t2];
}

// ---------------- Kernel 4: LN1 + QKV projection -> bf16 Q (pre-scaled), K, V^T
__global__ __launch_bounds__(128) void glb_ln_qkv_k(
    const float* __restrict__ xf,
    const float* __restrict__ wq, const float* __restrict__ bq,
    const float* __restrict__ wk, const float* __restrict__ bk,
    const float* __restrict__ wv, const float* __restrict__ bv,
    const float* __restrict__ g1, const float* __restrict__ be1,
    u16* __restrict__ qb, u16* __restrict__ kb, u16* __restrict__ vtb) {
  __shared__ float xs[8][CC];
  __shared__ float ys[8][CC];
  __shared__ float red[8][2];
  __shared__ u16 vsh[CC][8];
  const int t0 = blockIdx.x * 8;
  const int tid = threadIdx.x;
  for (int t2 = 0; t2 < 8; ++t2) xs[t2][tid] = xf[(t0 + t2) * CC + tid];
  __syncthreads();
  const int wvi = tid >> 6, lane = tid & 63;
  for (int t2 = wvi * 4; t2 < wvi * 4 + 4; ++t2) {
    const float v0 = xs[t2][lane], v1 = xs[t2][64 + lane];
    float s = v0 + v1, sq = v0 * v0 + v1 * v1;
#pragma unroll
    for (int off = 1; off < 64; off <<= 1) { s += __shfl_xor(s, off); sq += __shfl_xor(sq, off); }
    if (lane == 0) {
      const float mu = s * 0.0078125f;
      const float var = sq * 0.0078125f - mu * mu;
      red[t2][0] = mu; red[t2][1] = rsqrtf(var + 1e-5f);
    }
  }
  __syncthreads();
  {
    const float gg = g1[tid], bb = be1[tid];
    for (int t2 = 0; t2 < 8; ++t2)
      ys[t2][tid] = (xs[t2][tid] - red[t2][0]) * red[t2][1] * gg + bb;
  }
  __syncthreads();
  float aq[8], ak[8], av[8];
  {
    const float bqv = bq[tid], bkv = bk[tid], bvv = bv[tid];
    for (int t2 = 0; t2 < 8; ++t2) { aq[t2] = bqv; ak[t2] = bkv; av[t2] = bvv; }
  }
#pragma unroll 4
  for (int i2 = 0; i2 < CC; ++i2) {
    const float wqv = wq[i2 * CC + tid];
    const float wkv = wk[i2 * CC + tid];
    const float wvv = wv[i2 * CC + tid];
#pragma unroll
    for (int t2 = 0; t2 < 8; ++t2) {
      const float xv = ys[t2][i2];
      aq[t2] = fmaf(xv, wqv, aq[t2]);
      ak[t2] = fmaf(xv, wkv, ak[t2]);
      av[t2] = fmaf(xv, wvv, av[t2]);
    }
  }
  const int head = tid >> 5, d = tid & 31;
  const float scale = 0.17677669529663687f;  // fold 1/sqrt(dk) into Q
  for (int t2 = 0; t2 < 8; ++t2) {
    const int t = t0 + t2;
    const int b = t / S_GLB, s = t - b * S_GLB;
    const int o = ((b * NH + head) * S_GLB + s) * DK + d;
    qb[o] = f2bf(aq[t2] * scale);
    kb[o] = f2bf(ak[t2]);
    vsh[tid][t2] = f2bf(av[t2]);
  }
  __syncthreads();
  // V^T write: channel tid -> row (bh*32+d), 8 consecutive s
  {
    const int b = t0 / S_GLB;
    const int s0 = t0 - b * S_GLB;
    const size_t off = ((size_t)(b * NH + head) * DK + d) * S_GLB + s0;
    *reinterpret_cast<u16x4*>(&vtb[off]) = *reinterpret_cast<u16x4*>(&vsh[tid][0]);
    *reinterpret_cast<u16x4*>(&vtb[off + 4]) = *reinterpret_cast<u16x4*>(&vsh[tid][4]);
  }
}

// ---------------- Kernel 5: global flash attention, bf16 MFMA (S=3136, dk=32)
__global__ __launch_bounds__(256) void glb_attn_k(
    const u16* __restrict__ qb, const u16* __restrict__ kb,
    const u16* __restrict__ vtb, float* __restrict__ ao) {
  __shared__ u16 ksh[64][40];       // K tile [key][dk], padded
  __shared__ u16 vtsh[32][72];      // V^T tile [d][key], padded
  __shared__ u16 psh[4][16][72];    // per-wave P tile [q][key], padded
  const int tid = threadIdx.x;
  const int w = tid >> 6;
  const int lane = tid & 63;
  const int lo = lane & 15, hi = lane >> 4;
  const int bh = blockIdx.y;
  const int q0 = blockIdx.x * 64;

  // Q fragment: wave's 16 q-rows, all 32 k. row lo, 16B chunk hi.
  const bf16x8 qfrag = *reinterpret_cast<const bf16x8*>(
      &qb[((size_t)bh * S_GLB + q0 + w * 16 + lo) * DK + 8 * hi]);

  const u16* kg0 = kb + (size_t)bh * S_GLB * DK;
  const u16* vg0 = vtb + (size_t)bh * DK * S_GLB;

  float mreg[4], lreg[4];
  f32x4 oacc[2];
#pragma unroll
  for (int r = 0; r < 4; ++r) { mreg[r] = -1e30f; lreg[r] = 0.f; }
  oacc[0] = (f32x4){0.f, 0.f, 0.f, 0.f};
  oacc[1] = (f32x4){0.f, 0.f, 0.f, 0.f};
  const f32x4 zero4 = (f32x4){0.f, 0.f, 0.f, 0.f};

  const int krow = tid >> 2, kc = tid & 3;
  const int vrow = tid >> 3, vc = tid & 7;

  for (int kt = 0; kt < S_GLB / 64; ++kt) {
    __syncthreads();
    // stage K tile (64x32) and V^T tile (32x64)
    *reinterpret_cast<u16x8*>(&ksh[krow][kc * 8]) =
        *reinterpret_cast<const u16x8*>(&kg0[((size_t)kt * 64 + krow) * DK + kc * 8]);
    *reinterpret_cast<u16x8*>(&vtsh[vrow][vc * 8]) =
        *reinterpret_cast<const u16x8*>(&vg0[(size_t)vrow * S_GLB + kt * 64 + vc * 8]);
    __syncthreads();

    // QK^T: 4 sub-tiles of 16 keys
    f32x4 s4[4];
#pragma unroll
    for (int st = 0; st < 4; ++st) {
      const bf16x8 kfrag = *reinterpret_cast<const bf16x8*>(&ksh[st * 16 + lo][8 * hi]);
      s4[st] = __builtin_amdgcn_mfma_f32_16x16x32_bf16(qfrag, kfrag, zero4, 0, 0, 0);
    }

    // online softmax in C-layout regs: reg r -> q row hi*4+r, col lo (+16*st)
#pragma unroll
    for (int r = 0; r < 4; ++r) {
      float rm = fmaxf(fmaxf(s4[0][r], s4[1][r]), fmaxf(s4[2][r], s4[3][r]));
      rm = fmaxf(rm, __shfl_xor(rm, 1));
      rm = fmaxf(rm, __shfl_xor(rm, 2));
      rm = fmaxf(rm, __shfl_xor(rm, 4));
      rm = fmaxf(rm, __shfl_xor(rm, 8));
      const float mnew = fmaxf(mreg[r], rm);
      const float corr = __expf(mreg[r] - mnew);
      mreg[r] = mnew;
      float psum = 0.f;
#pragma unroll
      for (int st = 0; st < 4; ++st) {
        const float p = __expf(s4[st][r] - mnew);
        psum += p;
        psh[w][hi * 4 + r][st * 16 + lo] = f2bf(p);
      }
      psum += __shfl_xor(psum, 1);
      psum += __shfl_xor(psum, 2);
      psum += __shfl_xor(psum, 4);
      psum += __shfl_xor(psum, 8);
      lreg[r] = lreg[r] * corr + psum;
      oacc[0][r] *= corr;
      oacc[1][r] *= corr;
    }
    // psh written and read by the same wave; DS ops are wave-ordered.
    asm volatile("" ::: "memory");

    // PV: out[16q x 32d] += P[16q x 64kk] * V[64kk x 32d] (Vt rows = d)
#pragma unroll
    for (int kch = 0; kch < 2; ++kch) {
      const bf16x8 pa = *reinterpret_cast<const bf16x8*>(&psh[w][lo][kch * 32 + 8 * hi]);
      const bf16x8 v0 = *reinterpret_cast<const bf16x8*>(&vtsh[lo][kch * 32 + 8 * hi]);
      const bf16x8 v1 = *reinterpret_cast<const bf16x8*>(&vtsh[16 + lo][kch * 32 + 8 * hi]);
      oacc[0] = __builtin_amdgcn_mfma_f32_16x16x32_bf16(pa, v0, oacc[0], 0, 0, 0);
      oacc[1] = __builtin_amdgcn_mfma_f32_16x16x32_bf16(pa, v1, oacc[1], 0, 0, 0);
    }
  }

  // epilogue: normalize and write ao[t][head*32 + d]
  const int b = bh >> 2, head = bh & 3;
#pragma unroll
  for (int r = 0; r < 4; ++r) {
    const float rl = 1.0f / lreg[r];
    const int t = b * S_GLB + q0 + w * 16 + hi * 4 + r;
#pragma unroll
    for (int dt = 0; dt < 2; ++dt)
      ao[(size_t)t * CC + head * DK + dt * 16 + lo] = oacc[dt][r] * rl;
  }
}

// ---------------- Kernel 6: global out-projection + residual (in-place xf)
__global__ __launch_bounds__(128) void glb_proj_k(
    const float* __restrict__ ao, const float* __restrict__ wo,
    const float* __restrict__ bo, float* __restrict__ xf) {
  __shared__ float as_[8][CC];
  const int t0 = blockIdx.x * 8;
  const int tid = threadIdx.x;
  for (int t2 = 0; t2 < 8; ++t2) as_[t2][tid] = ao[(t0 + t2) * CC + tid];
  __syncthreads();
  float acc[8];
  { const float bov = bo[tid]; for (int t2 = 0; t2 < 8; ++t2) acc[t2] = bov; }
#pragma unroll 4
  for (int i2 = 0; i2 < CC; ++i2) {
    const float w_ = wo[i2 * CC + tid];
#pragma unroll
    for (int t2 = 0; t2 < 8; ++t2) acc[t2] = fmaf(as_[t2][i2], w_, acc[t2]);
  }
  for (int t2 = 0; t2 < 8; ++t2) {
    const int idx = (t0 + t2) * CC + tid;
    xf[idx] = xf[idx] + acc[t2];
  }
}

// ---------------- Kernel 7: LN2 + FC1 + exact gelu
__global__ __launch_bounds__(512) void mlp_fc1_k(
    const float* __restrict__ xf, const float* __restrict__ w1,
    const float* __restrict__ b1, const float* __restrict__ g2,
    const float* __restrict__ be2, float* __restrict__ h) {
  __shared__ float xs[8][CC];
  __shared__ float ys[8][CC];
  __shared__ float red[8][2];
  const int t0 = blockIdx.x * 8;
  const int tid = threadIdx.x;
  for (int e = tid; e < 8 * CC; e += 512) xs[e >> 7][e & 127] = xf[t0 * CC + e];
  __syncthreads();
  const int wvi = tid >> 6, lane = tid & 63;
  {
    const int t2 = wvi;
    const float v0 = xs[t2][lane], v1 = xs[t2][64 + lane];
    float s = v0 + v1, sq = v0 * v0 + v1 * v1;
#pragma unroll
    for (int off = 1; off < 64; off <<= 1) { s += __shfl_xor(s, off); sq += __shfl_xor(sq, off); }
    if (lane == 0) {
      const float mu = s * 0.0078125f;
      const float var = sq * 0.0078125f - mu * mu;
      red[t2][0] = mu; red[t2][1] = rsqrtf(var + 1e-5f);
    }
  }
  __syncthreads();
  for (int e = tid; e < 8 * CC; e += 512) {
    const int t2 = e >> 7, c = e & 127;
    ys[t2][c] = (xs[t2][c] - red[t2][0]) * red[t2][1] * g2[c] + be2[c];
  }
  __syncthreads();
  float acc[8];
  { const float bb = b1[tid]; for (int t2 = 0; t2 < 8; ++t2) acc[t2] = bb; }
#pragma unroll 4
  for (int i2 = 0; i2 < CC; ++i2) {
    const float w_ = w1[i2 * 512 + tid];
#pragma unroll
    for (int t2 = 0; t2 < 8; ++t2) acc[t2] = fmaf(ys[t2][i2], w_, acc[t2]);
  }
  for (int t2 = 0; t2 < 8; ++t2) {
    const float vph = acc[t2];
    h[(t0 + t2) * 512 + tid] = 0.5f * vph * (1.0f + erff(vph * 0.70710678118f));
  }
}

// ---------------- Kernel 8: FC2 + residual -> out
__global__ __launch_bounds__(128) void mlp_fc2_k(
    const float* __restrict__ h, const float* __restrict__ w2,
    const float* __restrict__ b2, const float* __restrict__ xf,
    float* __restrict__ out) {
  __shared__ float hs[8][512];
  const int t0 = blockIdx.x * 8;
  const int tid = threadIdx.x;
  for (int e = tid; e < 8 * 512; e += 128) hs[e >> 9][e & 511] = h[t0 * 512 + e];
  __syncthreads();
  float acc[8];
  for (int t2 = 0; t2 < 8; ++t2) acc[t2] = 0.f;
#pragma unroll 4
  for (int i2 = 0; i2 < 512; ++i2) {
    const float w_ = w2[i2 * CC + tid];
#pragma unroll
    for (int t2 = 0; t2 < 8; ++t2) acc[t2] = fmaf(hs[t2][i2], w_, acc[t2]);
  }
  const float bb = b2[tid];
  for (int t2 = 0; t2 < 8; ++t2) {
    const int idx = (t0 + t2) * CC + tid;
    out[idx] = xf[idx] + bb + acc[t2];
  }
}

extern "C" void kernel_launch(void* const* d_in, const int* in_sizes, int n_in,
                              void* d_out, int out_size, void* d_ws, size_t ws_size,
                              hipStream_t stream) {
  (void)in_sizes; (void)n_in; (void)out_size; (void)ws_size;
  const float* x   = (const float*)d_in[0];
  const float* wq  = (const float*)d_in[1];
  const float* bq  = (const float*)d_in[2];
  const float* wk  = (const float*)d_in[3];
  const float* bk  = (const float*)d_in[4];
  const float* wv  = (const float*)d_in[5];
  const float* bv  = (const float*)d_in[6];
  const float* wo  = (const float*)d_in[7];
  const float* bo  = (const float*)d_in[8];
  const float* w1  = (const float*)d_in[9];
  const float* b1  = (const float*)d_in[10];
  const float* w2  = (const float*)d_in[11];
  const float* b2  = (const float*)d_in[12];
  const float* g1  = (const float*)d_in[13];
  const float* be1 = (const float*)d_in[14];
  const float* g2  = (const float*)d_in[15];
  const float* be2 = (const float*)d_in[16];
  float* out = (float*)d_out;

  float* ws = (float*)d_ws;
  float* qf = ws;
  float* kf = qf + (size_t)NTOK * CC;
  float* vf = kf + (size_t)NTOK * CC;
  float* ao = vf + (size_t)NTOK * CC;
  float* xf = ao + (size_t)NTOK * CC;
  float* h  = xf + (size_t)NTOK * CC;
  // bf16 buffers overlaid on the (dead-by-then) window-path fp32 QKV regions
  u16* qb  = (u16*)qf;
  u16* kb  = (u16*)kf;
  u16* vtb = (u16*)vf;

  win_qkv_k<<<NTOK / 8, 128, 0, stream>>>(x, wq, bq, wk, bk, wv, bv, qf, kf, vf);
  win_attn_k<<<NWIN * NH, 256, 0, stream>>>(qf, kf, vf, ao);
  win_proj_k<<<NTOK / 8, 128, 0, stream>>>(ao, wo, bo, xf);
  glb_ln_qkv_k<<<NTOK / 8, 128, 0, stream>>>(xf, wq, bq, wk, bk, wv, bv, g1, be1, qb, kb, vtb);
  glb_attn_k<<<dim3(S_GLB / 64, 16), 256, 0, stream>>>(qb, kb, vtb, ao);
  glb_proj_k<<<NTOK / 8, 128, 0, stream>>>(ao, wo, bo, xf);
  mlp_fc1_k<<<NTOK / 8, 512, 0, stream>>>(xf, w1, b1, g2, be2, h);
  mlp_fc2_k<<<NTOK / 8, 128, 0, stream>>>(h, w2, b2, xf, out);
}

// Round 3
// 233.102 us; speedup vs baseline: 3.1462x; 1.4999x over previous
//
#include <hip/hip_runtime.h>
#include <hip/hip_bf16.h>
#include <math.h>

#define NH 4
#define DK 32
#define CC 128
#define HW 56
#define SHIFT 3
#define NTOK 12544   // 4*56*56 == 256*49
#define S_GLB 3136
#define NWIN 256

typedef unsigned short u16;
typedef short bf16x8 __attribute__((ext_vector_type(8)));
typedef unsigned short u16x8 __attribute__((ext_vector_type(8)));
typedef unsigned short u16x4 __attribute__((ext_vector_type(4)));
typedef float f32x4 __attribute__((ext_vector_type(4)));

static __device__ __forceinline__ u16 f2bf(float f) {
  unsigned int b = __builtin_bit_cast(unsigned int, f);
  return (u16)((b + 0x7FFFu + ((b >> 16) & 1u)) >> 16);
}

// ---------------- Kernel 0: transpose-convert weights fp32[R][C] -> bf16[C][R]
__global__ __launch_bounds__(256) void cvt_w_k(
    const float* __restrict__ in, u16* __restrict__ out, int R, int C) {
  const int o = blockIdx.x * 256 + threadIdx.x;
  if (o >= R * C) return;
  const int c = o / R, r = o % R;
  out[o] = f2bf(in[r * C + c]);
}

// ---------------- Kernel 1: shift + window-partition gather + QKV projection (fp32)
__global__ __launch_bounds__(128) void win_qkv_k(
    const float* __restrict__ x,
    const float* __restrict__ wq, const float* __restrict__ bq,
    const float* __restrict__ wk, const float* __restrict__ bk,
    const float* __restrict__ wv, const float* __restrict__ bv,
    float* __restrict__ q, float* __restrict__ k, float* __restrict__ v) {
  __shared__ float xs[8][CC];
  const int t0 = blockIdx.x * 8;
  const int tid = threadIdx.x;
  for (int t2 = 0; t2 < 8; ++t2) {
    const int t = t0 + t2;
    const int win = t / 49, tok = t % 49;
    const int b = win >> 6, wrem = win & 63;
    const int wi = wrem >> 3, wj = wrem & 7;
    const int i = tok / 7, j = tok % 7;
    int hh = wi * 7 + i + SHIFT; if (hh >= HW) hh -= HW;
    int ww = wj * 7 + j + SHIFT; if (ww >= HW) ww -= HW;
    xs[t2][tid] = x[((b * HW + hh) * HW + ww) * CC + tid];
  }
  __syncthreads();
  float aq[8], ak[8], av[8];
  {
    const float bqv = bq[tid], bkv = bk[tid], bvv = bv[tid];
    for (int t2 = 0; t2 < 8; ++t2) { aq[t2] = bqv; ak[t2] = bkv; av[t2] = bvv; }
  }
#pragma unroll 4
  for (int i2 = 0; i2 < CC; ++i2) {
    const float wqv = wq[i2 * CC + tid];
    const float wkv = wk[i2 * CC + tid];
    const float wvv = wv[i2 * CC + tid];
#pragma unroll
    for (int t2 = 0; t2 < 8; ++t2) {
      const float xv = xs[t2][i2];
      aq[t2] = fmaf(xv, wqv, aq[t2]);
      ak[t2] = fmaf(xv, wkv, ak[t2]);
      av[t2] = fmaf(xv, wvv, av[t2]);
    }
  }
  const int head = tid >> 5, d = tid & 31;
  for (int t2 = 0; t2 < 8; ++t2) {
    const int t = t0 + t2;
    const int win = t / 49, tok = t % 49;
    const int o = ((win * NH + head) * 49 + tok) * DK + d;
    q[o] = aq[t2]; k[o] = ak[t2]; v[o] = av[t2];
  }
}

// ---------------- Kernel 2: per-(window,head) attention, s=49 (fp32)
__global__ __launch_bounds__(256) void win_attn_k(
    const float* __restrict__ q, const float* __restrict__ k,
    const float* __restrict__ v, float* __restrict__ ao) {
  __shared__ float qs[49][33], ks[49][33], vs[49][33];
  __shared__ float ss[49][49];
  __shared__ float rinv[49];
  const int wh = blockIdx.x;
  const int tid = threadIdx.x;
  const float* qg = q + wh * 49 * DK;
  const float* kg = k + wh * 49 * DK;
  const float* vg = v + wh * 49 * DK;
  for (int e = tid; e < 49 * DK; e += 256) {
    const int r = e >> 5, d = e & 31;
    qs[r][d] = qg[e]; ks[r][d] = kg[e]; vs[r][d] = vg[e];
  }
  __syncthreads();
  const float scale = 0.17677669529663687f;
  for (int e = tid; e < 49 * 49; e += 256) {
    const int qi = e / 49, ki = e % 49;
    float s = 0.f;
#pragma unroll
    for (int i = 0; i < DK; ++i) s = fmaf(qs[qi][i], ks[ki][i], s);
    ss[qi][ki] = s * scale;
  }
  __syncthreads();
  if (tid < 49) {
    float mx = -1e30f;
    for (int i = 0; i < 49; ++i) mx = fmaxf(mx, ss[tid][i]);
    float sum = 0.f;
    for (int i = 0; i < 49; ++i) { const float p = __expf(ss[tid][i] - mx); ss[tid][i] = p; sum += p; }
    rinv[tid] = 1.0f / sum;
  }
  __syncthreads();
  const int win = wh >> 2, head = wh & 3;
  for (int e = tid; e < 49 * DK; e += 256) {
    const int qi = e >> 5, d = e & 31;
    float o = 0.f;
#pragma unroll
    for (int i = 0; i < 49; ++i) o = fmaf(ss[qi][i], vs[i][d], o);
    ao[(win * 49 + qi) * CC + head * DK + d] = o * rinv[qi];
  }
}

// ---------------- Kernel 3: window-reverse + unshift + output projection (fp32)
__global__ __launch_bounds__(128) void win_proj_k(
    const float* __restrict__ ao, const float* __restrict__ wo,
    const float* __restrict__ bo, float* __restrict__ xf) {
  __shared__ float as_[8][CC];
  const int t0 = blockIdx.x * 8;
  const int tid = threadIdx.x;
  for (int t2 = 0; t2 < 8; ++t2) {
    const int t = t0 + t2;
    const int b = t / S_GLB, rem = t % S_GLB;
    const int h = rem / HW, w = rem % HW;
    int hs = h + (HW - SHIFT); if (hs >= HW) hs -= HW;
    int wsp = w + (HW - SHIFT); if (wsp >= HW) wsp -= HW;
    const int wi = hs / 7, ii = hs % 7, wj = wsp / 7, jj = wsp % 7;
    const int win = (b << 6) + wi * 8 + wj;
    const int tok = ii * 7 + jj;
    as_[t2][tid] = ao[(win * 49 + tok) * CC + tid];
  }
  __syncthreads();
  float acc[8];
  { const float bov = bo[tid]; for (int t2 = 0; t2 < 8; ++t2) acc[t2] = bov; }
#pragma unroll 4
  for (int i2 = 0; i2 < CC; ++i2) {
    const float w_ = wo[i2 * CC + tid];
#pragma unroll
    for (int t2 = 0; t2 < 8; ++t2) acc[t2] = fmaf(as_[t2][i2], w_, acc[t2]);
  }
  for (int t2 = 0; t2 < 8; ++t2) xf[(t0 + t2) * CC + tid] = acc[t2];
}

// ---------------- Kernel 4: LN1 + QKV projection -> bf16 Q (pre-scaled), K, V^T
__global__ __launch_bounds__(128) void glb_ln_qkv_k(
    const float* __restrict__ xf,
    const float* __restrict__ wq, const float* __restrict__ bq,
    const float* __restrict__ wk, const float* __restrict__ bk,
    const float* __restrict__ wv, const float* __restrict__ bv,
    const float* __restrict__ g1, const float* __restrict__ be1,
    u16* __restrict__ qb, u16* __restrict__ kb, u16* __restrict__ vtb) {
  __shared__ float xs[8][CC];
  __shared__ float ys[8][CC];
  __shared__ float red[8][2];
  __shared__ u16 vsh[CC][8];
  const int t0 = blockIdx.x * 8;
  const int tid = threadIdx.x;
  for (int t2 = 0; t2 < 8; ++t2) xs[t2][tid] = xf[(t0 + t2) * CC + tid];
  __syncthreads();
  const int wvi = tid >> 6, lane = tid & 63;
  for (int t2 = wvi * 4; t2 < wvi * 4 + 4; ++t2) {
    const float v0 = xs[t2][lane], v1 = xs[t2][64 + lane];
    float s = v0 + v1, sq = v0 * v0 + v1 * v1;
#pragma unroll
    for (int off = 1; off < 64; off <<= 1) { s += __shfl_xor(s, off); sq += __shfl_xor(sq, off); }
    if (lane == 0) {
      const float mu = s * 0.0078125f;
      const float var = sq * 0.0078125f - mu * mu;
      red[t2][0] = mu; red[t2][1] = rsqrtf(var + 1e-5f);
    }
  }
  __syncthreads();
  {
    const float gg = g1[tid], bb = be1[tid];
    for (int t2 = 0; t2 < 8; ++t2)
      ys[t2][tid] = (xs[t2][tid] - red[t2][0]) * red[t2][1] * gg + bb;
  }
  __syncthreads();
  float aq[8], ak[8], av[8];
  {
    const float bqv = bq[tid], bkv = bk[tid], bvv = bv[tid];
    for (int t2 = 0; t2 < 8; ++t2) { aq[t2] = bqv; ak[t2] = bkv; av[t2] = bvv; }
  }
#pragma unroll 4
  for (int i2 = 0; i2 < CC; ++i2) {
    const float wqv = wq[i2 * CC + tid];
    const float wkv = wk[i2 * CC + tid];
    const float wvv = wv[i2 * CC + tid];
#pragma unroll
    for (int t2 = 0; t2 < 8; ++t2) {
      const float xv = ys[t2][i2];
      aq[t2] = fmaf(xv, wqv, aq[t2]);
      ak[t2] = fmaf(xv, wkv, ak[t2]);
      av[t2] = fmaf(xv, wvv, av[t2]);
    }
  }
  const int head = tid >> 5, d = tid & 31;
  const float scale = 0.17677669529663687f;
  for (int t2 = 0; t2 < 8; ++t2) {
    const int t = t0 + t2;
    const int b = t / S_GLB, s = t - b * S_GLB;
    const int o = ((b * NH + head) * S_GLB + s) * DK + d;
    qb[o] = f2bf(aq[t2] * scale);
    kb[o] = f2bf(ak[t2]);
    vsh[tid][t2] = f2bf(av[t2]);
  }
  __syncthreads();
  {
    const int b = t0 / S_GLB;
    const int s0 = t0 - b * S_GLB;
    const size_t off = ((size_t)(b * NH + head) * DK + d) * S_GLB + s0;
    *reinterpret_cast<u16x4*>(&vtb[off]) = *reinterpret_cast<u16x4*>(&vsh[tid][0]);
    *reinterpret_cast<u16x4*>(&vtb[off + 4]) = *reinterpret_cast<u16x4*>(&vsh[tid][4]);
  }
}

// ---------------- Kernel 5: global flash attention, swapped-QK^T bf16 MFMA
__global__ __launch_bounds__(256) void glb_attn_k(
    const u16* __restrict__ qb, const u16* __restrict__ kb,
    const u16* __restrict__ vtb, float* __restrict__ ao) {
  __shared__ __align__(16) u16 ksh[64][40];    // K tile [key][dk]
  __shared__ __align__(16) u16 vtsh[32][72];   // V^T tile [d][key]
  __shared__ __align__(16) u16 psh[4][16][72]; // per-wave P tile [q][key]
  __shared__ __align__(16) float crr[4][16];   // per-wave corr[q]
  __shared__ __align__(16) float lsh[4][16];   // per-wave l[q]
  const int tid = threadIdx.x;
  const int w = tid >> 6;
  const int lane = tid & 63;
  const int lo = lane & 15, hi = lane >> 4;
  const int bh = blockIdx.y;
  const int q0 = blockIdx.x * 64;

  const bf16x8 qfrag = *reinterpret_cast<const bf16x8*>(
      &qb[((size_t)bh * S_GLB + q0 + w * 16 + lo) * DK + 8 * hi]);

  const u16* kg0 = kb + (size_t)bh * S_GLB * DK;
  const u16* vg0 = vtb + (size_t)bh * DK * S_GLB;

  float m = -1e30f, l = 0.f;
  f32x4 oacc[2];
  oacc[0] = (f32x4){0.f, 0.f, 0.f, 0.f};
  oacc[1] = (f32x4){0.f, 0.f, 0.f, 0.f};
  const f32x4 zero4 = (f32x4){0.f, 0.f, 0.f, 0.f};

  const int krow = tid >> 2, kc = tid & 3;
  const int vrow = tid >> 3, vc = tid & 7;

  for (int kt = 0; kt < S_GLB / 64; ++kt) {
    __syncthreads();
    *reinterpret_cast<u16x8*>(&ksh[krow][kc * 8]) =
        *reinterpret_cast<const u16x8*>(&kg0[((size_t)kt * 64 + krow) * DK + kc * 8]);
    *reinterpret_cast<u16x8*>(&vtsh[vrow][vc * 8]) =
        *reinterpret_cast<const u16x8*>(&vg0[(size_t)vrow * S_GLB + kt * 64 + vc * 8]);
    __syncthreads();

    // S^T = K * Q^T : lane (hi,lo) reg r holds S[key=st*16+hi*4+r][q=lo]
    f32x4 s4[4];
#pragma unroll
    for (int st = 0; st < 4; ++st) {
      const bf16x8 kfrag = *reinterpret_cast<const bf16x8*>(&ksh[st * 16 + lo][8 * hi]);
      s4[st] = __builtin_amdgcn_mfma_f32_16x16x32_bf16(kfrag, qfrag, zero4, 0, 0, 0);
    }

    // row-max over 16 in-register scores + 2 shuffles (across hi groups)
    float rm = fmaxf(fmaxf(fmaxf(s4[0][0], s4[0][1]), fmaxf(s4[0][2], s4[0][3])),
                     fmaxf(fmaxf(s4[1][0], s4[1][1]), fmaxf(s4[1][2], s4[1][3])));
    rm = fmaxf(rm, fmaxf(fmaxf(fmaxf(s4[2][0], s4[2][1]), fmaxf(s4[2][2], s4[2][3])),
                         fmaxf(fmaxf(s4[3][0], s4[3][1]), fmaxf(s4[3][2], s4[3][3]))));
    rm = fmaxf(rm, __shfl_xor(rm, 16));
    rm = fmaxf(rm, __shfl_xor(rm, 32));
    const float mnew = fmaxf(m, rm);
    const float corr = __expf(m - mnew);
    m = mnew;

    float psum = 0.f;
#pragma unroll
    for (int st = 0; st < 4; ++st) {
      u16x4 pk;
#pragma unroll
      for (int r = 0; r < 4; ++r) {
        const float p = __expf(s4[st][r] - mnew);
        psum += p;
        pk[r] = f2bf(p);
      }
      *reinterpret_cast<u16x4*>(&psh[w][lo][st * 16 + hi * 4]) = pk;
    }
    psum += __shfl_xor(psum, 16);
    psum += __shfl_xor(psum, 32);
    l = l * corr + psum;
    if (hi == 0) crr[w][lo] = corr;
    asm volatile("" ::: "memory");  // same-wave DS ordering; block compiler reorder

    // rescale O with corr for q = hi*4+r (broadcast read from LDS)
    const f32x4 c4 = *reinterpret_cast<const f32x4*>(&crr[w][hi * 4]);
#pragma unroll
    for (int r = 0; r < 4; ++r) { oacc[0][r] *= c4[r]; oacc[1][r] *= c4[r]; }

    // PV: out[16q x 32d] += P[16q x 64k] * V^T rows d
#pragma unroll
    for (int kch = 0; kch < 2; ++kch) {
      const bf16x8 pa = *reinterpret_cast<const bf16x8*>(&psh[w][lo][kch * 32 + 8 * hi]);
      const bf16x8 v0 = *reinterpret_cast<const bf16x8*>(&vtsh[lo][kch * 32 + 8 * hi]);
      const bf16x8 v1 = *reinterpret_cast<const bf16x8*>(&vtsh[16 + lo][kch * 32 + 8 * hi]);
      oacc[0] = __builtin_amdgcn_mfma_f32_16x16x32_bf16(pa, v0, oacc[0], 0, 0, 0);
      oacc[1] = __builtin_amdgcn_mfma_f32_16x16x32_bf16(pa, v1, oacc[1], 0, 0, 0);
    }
  }

  if (hi == 0) lsh[w][lo] = l;
  asm volatile("" ::: "memory");
  const f32x4 l4 = *reinterpret_cast<const f32x4*>(&lsh[w][hi * 4]);
  const int b = bh >> 2, head = bh & 3;
#pragma unroll
  for (int r = 0; r < 4; ++r) {
    const float rl = 1.0f / l4[r];
    const int t = b * S_GLB + q0 + w * 16 + hi * 4 + r;
#pragma unroll
    for (int dt = 0; dt < 2; ++dt)
      ao[(size_t)t * CC + head * DK + dt * 16 + lo] = oacc[dt][r] * rl;
  }
}

// ---------------- Kernel 6: global out-projection + residual (in-place xf)
__global__ __launch_bounds__(128) void glb_proj_k(
    const float* __restrict__ ao, const float* __restrict__ wo,
    const float* __restrict__ bo, float* __restrict__ xf) {
  __shared__ float as_[8][CC];
  const int t0 = blockIdx.x * 8;
  const int tid = threadIdx.x;
  for (int t2 = 0; t2 < 8; ++t2) as_[t2][tid] = ao[(t0 + t2) * CC + tid];
  __syncthreads();
  float acc[8];
  { const float bov = bo[tid]; for (int t2 = 0; t2 < 8; ++t2) acc[t2] = bov; }
#pragma unroll 4
  for (int i2 = 0; i2 < CC; ++i2) {
    const float w_ = wo[i2 * CC + tid];
#pragma unroll
    for (int t2 = 0; t2 < 8; ++t2) acc[t2] = fmaf(as_[t2][i2], w_, acc[t2]);
  }
  for (int t2 = 0; t2 < 8; ++t2) {
    const int idx = (t0 + t2) * CC + tid;
    xf[idx] = xf[idx] + acc[t2];
  }
}

// ---------------- Kernel 7: LN2 -> bf16
__global__ __launch_bounds__(128) void ln2_k(
    const float* __restrict__ xf, const float* __restrict__ g2,
    const float* __restrict__ be2, u16* __restrict__ ybf) {
  __shared__ float xs[8][CC];
  __shared__ float red[8][2];
  const int t0 = blockIdx.x * 8;
  const int tid = threadIdx.x;
  for (int t2 = 0; t2 < 8; ++t2) xs[t2][tid] = xf[(t0 + t2) * CC + tid];
  __syncthreads();
  const int wvi = tid >> 6, lane = tid & 63;
  for (int t2 = wvi * 4; t2 < wvi * 4 + 4; ++t2) {
    const float v0 = xs[t2][lane], v1 = xs[t2][64 + lane];
    float s = v0 + v1, sq = v0 * v0 + v1 * v1;
#pragma unroll
    for (int off = 1; off < 64; off <<= 1) { s += __shfl_xor(s, off); sq += __shfl_xor(sq, off); }
    if (lane == 0) {
      const float mu = s * 0.0078125f;
      const float var = sq * 0.0078125f - mu * mu;
      red[t2][0] = mu; red[t2][1] = rsqrtf(var + 1e-5f);
    }
  }
  __syncthreads();
  const float gg = g2[tid], bb = be2[tid];
  for (int t2 = 0; t2 < 8; ++t2)
    ybf[(t0 + t2) * CC + tid] = f2bf((xs[t2][tid] - red[t2][0]) * red[t2][1] * gg + bb);
}

// ---------------- Kernel 8: GEMM1 [NTOK,128]@[128,512] + gelu -> bf16
__global__ __launch_bounds__(256) void gemm1_k(
    const u16* __restrict__ ybf, const u16* __restrict__ w1t,
    const float* __restrict__ b1, u16* __restrict__ hb) {
  __shared__ __align__(16) u16 xs[64][136];
  __shared__ __align__(16) u16 wt[64][136];
  const int tid = threadIdx.x;
  const int w = tid >> 6, lane = tid & 63;
  const int lo = lane & 15, hi = lane >> 4;
  const int m0 = blockIdx.x * 64, n0 = blockIdx.y * 64;
  {
    const int r = tid >> 2, sg = tid & 3;
    const u16* src_x = &ybf[(size_t)(m0 + r) * CC + sg * 32];
    const u16* src_w = &w1t[(size_t)(n0 + r) * CC + sg * 32];
#pragma unroll
    for (int j = 0; j < 4; ++j) {
      *reinterpret_cast<u16x8*>(&xs[r][sg * 32 + j * 8]) = *reinterpret_cast<const u16x8*>(&src_x[j * 8]);
      *reinterpret_cast<u16x8*>(&wt[r][sg * 32 + j * 8]) = *reinterpret_cast<const u16x8*>(&src_w[j * 8]);
    }
  }
  __syncthreads();
  f32x4 acc[4];
#pragma unroll
  for (int st = 0; st < 4; ++st) {
    const float bv = b1[n0 + st * 16 + lo];
    acc[st] = (f32x4){bv, bv, bv, bv};
  }
#pragma unroll
  for (int kk = 0; kk < 4; ++kk) {
    const bf16x8 af = *reinterpret_cast<const bf16x8*>(&xs[w * 16 + lo][kk * 32 + 8 * hi]);
#pragma unroll
    for (int st = 0; st < 4; ++st) {
      const bf16x8 bfr = *reinterpret_cast<const bf16x8*>(&wt[st * 16 + lo][kk * 32 + 8 * hi]);
      acc[st] = __builtin_amdgcn_mfma_f32_16x16x32_bf16(af, bfr, acc[st], 0, 0, 0);
    }
  }
#pragma unroll
  for (int st = 0; st < 4; ++st) {
#pragma unroll
    for (int r = 0; r < 4; ++r) {
      const float val = acc[st][r];
      const float gel = 0.5f * val * (1.0f + erff(val * 0.70710678118f));
      hb[(size_t)(m0 + w * 16 + hi * 4 + r) * 512 + n0 + st * 16 + lo] = f2bf(gel);
    }
  }
}

// ---------------- Kernel 9: GEMM2 [NTOK,512]@[512,128] + residual -> out
__global__ __launch_bounds__(128) void gemm2_k(
    const u16* __restrict__ hb, const u16* __restrict__ w2t,
    const float* __restrict__ b2, const float* __restrict__ xf,
    float* __restrict__ out) {
  __shared__ __align__(16) u16 xs[32][136];
  __shared__ __align__(16) u16 wt[64][136];
  const int tid = threadIdx.x;
  const int w = tid >> 6, lane = tid & 63;
  const int lo = lane & 15, hi = lane >> 4;
  const int m0 = blockIdx.x * 32, n0 = blockIdx.y * 64;
  f32x4 acc[4];
#pragma unroll
  for (int st = 0; st < 4; ++st) {
    const float bv = b2[n0 + st * 16 + lo];
    acc[st] = (f32x4){bv, bv, bv, bv};
  }
  for (int kc = 0; kc < 4; ++kc) {
    __syncthreads();
    {
      const int r = tid >> 2, sg = tid & 3;   // 32 rows x 128 cols
      const u16* src_x = &hb[(size_t)(m0 + r) * 512 + kc * 128 + sg * 32];
#pragma unroll
      for (int j = 0; j < 4; ++j)
        *reinterpret_cast<u16x8*>(&xs[r][sg * 32 + j * 8]) = *reinterpret_cast<const u16x8*>(&src_x[j * 8]);
      const int r2 = tid >> 1, sg2 = tid & 1; // 64 rows x 128 cols
      const u16* src_w = &w2t[(size_t)(n0 + r2) * 512 + kc * 128 + sg2 * 64];
#pragma unroll
      for (int j = 0; j < 8; ++j)
        *reinterpret_cast<u16x8*>(&wt[r2][sg2 * 64 + j * 8]) = *reinterpret_cast<const u16x8*>(&src_w[j * 8]);
    }
    __syncthreads();
#pragma unroll
    for (int kk = 0; kk < 4; ++kk) {
      const bf16x8 af = *reinterpret_cast<const bf16x8*>(&xs[w * 16 + lo][kk * 32 + 8 * hi]);
#pragma unroll
      for (int st = 0; st < 4; ++st) {
        const bf16x8 bfr = *reinterpret_cast<const bf16x8*>(&wt[st * 16 + lo][kk * 32 + 8 * hi]);
        acc[st] = __builtin_amdgcn_mfma_f32_16x16x32_bf16(af, bfr, acc[st], 0, 0, 0);
      }
    }
  }
#pragma unroll
  for (int st = 0; st < 4; ++st) {
#pragma unroll
    for (int r = 0; r < 4; ++r) {
      const size_t idx = (size_t)(m0 + w * 16 + hi * 4 + r) * CC + n0 + st * 16 + lo;
      out[idx] = xf[idx] + acc[st][r];
    }
  }
}

extern "C" void kernel_launch(void* const* d_in, const int* in_sizes, int n_in,
                              void* d_out, int out_size, void* d_ws, size_t ws_size,
                              hipStream_t stream) {
  (void)in_sizes; (void)n_in; (void)out_size; (void)ws_size;
  const float* x   = (const float*)d_in[0];
  const float* wq  = (const float*)d_in[1];
  const float* bq  = (const float*)d_in[2];
  const float* wk  = (const float*)d_in[3];
  const float* bk  = (const float*)d_in[4];
  const float* wv  = (const float*)d_in[5];
  const float* bv  = (const float*)d_in[6];
  const float* wo  = (const float*)d_in[7];
  const float* bo  = (const float*)d_in[8];
  const float* w1  = (const float*)d_in[9];
  const float* b1  = (const float*)d_in[10];
  const float* w2  = (const float*)d_in[11];
  const float* b2  = (const float*)d_in[12];
  const float* g1  = (const float*)d_in[13];
  const float* be1 = (const float*)d_in[14];
  const float* g2  = (const float*)d_in[15];
  const float* be2 = (const float*)d_in[16];
  float* out = (float*)d_out;

  float* ws = (float*)d_ws;
  float* qf = ws;
  float* kf = qf + (size_t)NTOK * CC;
  float* vf = kf + (size_t)NTOK * CC;
  float* ao = vf + (size_t)NTOK * CC;
  float* xf = ao + (size_t)NTOK * CC;
  u16* ybf = (u16*)(xf + (size_t)NTOK * CC);
  u16* hb  = ybf + (size_t)NTOK * CC;
  u16* w1t = hb + (size_t)NTOK * 512;
  u16* w2t = w1t + (size_t)CC * 512;
  u16* qb  = (u16*)qf;
  u16* kb  = (u16*)kf;
  u16* vtb = (u16*)vf;

  cvt_w_k<<<(CC * 512 + 255) / 256, 256, 0, stream>>>(w1, w1t, CC, 512);
  cvt_w_k<<<(512 * CC + 255) / 256, 256, 0, stream>>>(w2, w2t, 512, CC);
  win_qkv_k<<<NTOK / 8, 128, 0, stream>>>(x, wq, bq, wk, bk, wv, bv, qf, kf, vf);
  win_attn_k<<<NWIN * NH, 256, 0, stream>>>(qf, kf, vf, ao);
  win_proj_k<<<NTOK / 8, 128, 0, stream>>>(ao, wo, bo, xf);
  glb_ln_qkv_k<<<NTOK / 8, 128, 0, stream>>>(xf, wq, bq, wk, bk, wv, bv, g1, be1, qb, kb, vtb);
  glb_attn_k<<<dim3(S_GLB / 64, 16), 256, 0, stream>>>(qb, kb, vtb, ao);
  glb_proj_k<<<NTOK / 8, 128, 0, stream>>>(ao, wo, bo, xf);
  ln2_k<<<NTOK / 8, 128, 0, stream>>>(xf, g2, be2, ybf);
  gemm1_k<<<dim3(NTOK / 64, 8), 256, 0, stream>>>(ybf, w1t, b1, hb);
  gemm2_k<<<dim3(NTOK / 32, 2), 128, 0, stream>>>(hb, w2t, b2, xf, out);
}

// Round 4
// 213.996 us; speedup vs baseline: 3.4271x; 1.0893x over previous
//
#include <hip/hip_runtime.h>
#include <hip/hip_bf16.h>
#include <math.h>

#define NH 4
#define DK 32
#define CC 128
#define HW 56
#define SHIFT 3
#define NTOK 12544   // 4*56*56 == 256*49
#define S_GLB 3136
#define VTW_STRIDE 12608
#define SCALE_L2E 0.25503488f  // log2(e)/sqrt(32): exp2-domain softmax scale

typedef unsigned short u16;
typedef short bf16x8 __attribute__((ext_vector_type(8)));
typedef unsigned short u16x8 __attribute__((ext_vector_type(8)));
typedef float f32x4 __attribute__((ext_vector_type(4)));

static __device__ __forceinline__ u16 f2bf(float f) {
  unsigned int b = __builtin_bit_cast(unsigned int, f);
  return (u16)((b + 0x7FFFu + ((b >> 16) & 1u)) >> 16);
}
static __device__ __forceinline__ unsigned pk2bf(float a, float b) {
  unsigned r;
  asm("v_cvt_pk_bf16_f32 %0, %1, %2" : "=v"(r) : "v"(a), "v"(b));
  return r;
}
static __device__ __forceinline__ float fexp2(float x) {
  float r;
  asm("v_exp_f32 %0, %1" : "=v"(r) : "v"(x));
  return r;
}

// ---------------- cvt: four 128x128 fp32 [in][out] -> bf16 [out][in]
__global__ __launch_bounds__(256) void cvt4_k(
    const float* __restrict__ wq, const float* __restrict__ wk,
    const float* __restrict__ wv, const float* __restrict__ wo,
    u16* __restrict__ wqkvt, u16* __restrict__ wot) {
  const int idx = blockIdx.x * 256 + threadIdx.x;
  const int which = idx >> 14, o = idx & 16383;
  const int c = o >> 7, r = o & 127;
  const float* src = (which == 0) ? wq : (which == 1) ? wk : (which == 2) ? wv : wo;
  u16* dst = (which < 3) ? (wqkvt + which * 16384) : wot;
  dst[o] = f2bf(src[r * 128 + c]);
}

// ---------------- cvt: generic fp32 [R][C] -> bf16 [C][R]
__global__ __launch_bounds__(256) void cvt_w_k(
    const float* __restrict__ in, u16* __restrict__ out, int R, int C) {
  const int o = blockIdx.x * 256 + threadIdx.x;
  if (o >= R * C) return;
  const int c = o / R, r = o % R;
  out[o] = f2bf(in[r * C + c]);
}

// ---------------- shift + window-partition gather -> bf16 [t_w][128]
__global__ __launch_bounds__(256) void win_gather_k(
    const float* __restrict__ x, u16* __restrict__ xg) {
  const int t = blockIdx.x * 2 + (threadIdx.x >> 7);
  const int c = threadIdx.x & 127;
  const int win = t / 49, tok = t % 49;
  const int b = win >> 6, wrem = win & 63;
  const int wi = wrem >> 3, wj = wrem & 7;
  const int i = tok / 7, j = tok % 7;
  int hh = wi * 7 + i + SHIFT; if (hh >= HW) hh -= HW;
  int ww = wj * 7 + j + SHIFT; if (ww >= HW) ww -= HW;
  xg[(size_t)t * CC + c] = f2bf(x[((size_t)(b * HW + hh) * HW + ww) * CC + c]);
}

// ---------------- fused QKV GEMM. PATH 0: window layout, PATH 1: global layout.
// y-grid: widx = y>>1 (0=q,1=k,2=v), n0 = (y&1)*64.
// v computed operand-swapped so V^T writes are (mostly) contiguous.
template <int PATH>
__global__ __launch_bounds__(256) void qkv_gemm_k(
    const u16* __restrict__ xin, const u16* __restrict__ wqkvt,
    const float* __restrict__ bq, const float* __restrict__ bk,
    const float* __restrict__ bv,
    u16* __restrict__ qo, u16* __restrict__ ko, u16* __restrict__ vto) {
  __shared__ __align__(16) u16 xs[64][136];
  __shared__ __align__(16) u16 wt[64][136];
  const int tid = threadIdx.x;
  const int w = tid >> 6, lane = tid & 63;
  const int lo = lane & 15, hi = lane >> 4, hi4 = hi * 4;
  const int m0 = blockIdx.x * 64;
  const int widx = blockIdx.y >> 1;
  const int n0 = (blockIdx.y & 1) * 64;
  {
    const int r = tid >> 2, sg = tid & 3;
    const u16* sx = &xin[(size_t)(m0 + r) * CC + sg * 32];
    const u16* sw = &wqkvt[(size_t)widx * CC * CC + (size_t)(n0 + r) * CC + sg * 32];
#pragma unroll
    for (int j = 0; j < 4; ++j) {
      *reinterpret_cast<u16x8*>(&xs[r][sg * 32 + j * 8]) = *reinterpret_cast<const u16x8*>(&sx[j * 8]);
      *reinterpret_cast<u16x8*>(&wt[r][sg * 32 + j * 8]) = *reinterpret_cast<const u16x8*>(&sw[j * 8]);
    }
  }
  __syncthreads();
  if (widx < 2) {
    const float* bias = (widx == 0) ? bq : bk;
    u16* outp = (widx == 0) ? qo : ko;
    const float oscale = (widx == 0) ? SCALE_L2E : 1.0f;
    f32x4 acc[4];
#pragma unroll
    for (int st = 0; st < 4; ++st) {
      const float b_ = bias[n0 + st * 16 + lo];
      acc[st] = (f32x4){b_, b_, b_, b_};
    }
#pragma unroll
    for (int kk = 0; kk < 4; ++kk) {
      const bf16x8 af = *reinterpret_cast<const bf16x8*>(&xs[w * 16 + lo][kk * 32 + 8 * hi]);
#pragma unroll
      for (int st = 0; st < 4; ++st) {
        const bf16x8 bfr = *reinterpret_cast<const bf16x8*>(&wt[st * 16 + lo][kk * 32 + 8 * hi]);
        acc[st] = __builtin_amdgcn_mfma_f32_16x16x32_bf16(af, bfr, acc[st], 0, 0, 0);
      }
    }
#pragma unroll
    for (int r = 0; r < 4; ++r) {
      const int mm = m0 + w * 16 + hi4 + r;
      size_t rowbase;
      size_t hstride;
      if (PATH == 0) {
        const int win = mm / 49, tok = mm - win * 49;
        rowbase = ((size_t)(win * 4) * 49 + tok) * DK;
        hstride = (size_t)49 * DK;
      } else {
        const int b = mm / S_GLB, s = mm - b * S_GLB;
        rowbase = ((size_t)(b * 4) * S_GLB + s) * DK;
        hstride = (size_t)S_GLB * DK;
      }
#pragma unroll
      for (int st = 0; st < 4; ++st) {
        const int c = n0 + st * 16 + lo, h = c >> 5, d = c & 31;
        outp[rowbase + (size_t)h * hstride + d] = f2bf(acc[st][r] * oscale);
      }
    }
  } else {
    // swapped: A = weight rows (channels), B = x rows (tokens)
    f32x4 bias4;
#pragma unroll
    for (int r = 0; r < 4; ++r) bias4[r] = bv[n0 + w * 16 + hi4 + r];
    f32x4 acc[4];
#pragma unroll
    for (int st = 0; st < 4; ++st) acc[st] = bias4;
#pragma unroll
    for (int kk = 0; kk < 4; ++kk) {
      const bf16x8 af = *reinterpret_cast<const bf16x8*>(&wt[w * 16 + lo][kk * 32 + 8 * hi]);
#pragma unroll
      for (int st = 0; st < 4; ++st) {
        const bf16x8 bfr = *reinterpret_cast<const bf16x8*>(&xs[st * 16 + lo][kk * 32 + 8 * hi]);
        acc[st] = __builtin_amdgcn_mfma_f32_16x16x32_bf16(af, bfr, acc[st], 0, 0, 0);
      }
    }
#pragma unroll
    for (int st = 0; st < 4; ++st) {
      const int mm = m0 + st * 16 + lo;  // token
#pragma unroll
      for (int r = 0; r < 4; ++r) {
        const int c = n0 + w * 16 + hi4 + r;
        if (PATH == 0) {
          vto[(size_t)c * VTW_STRIDE + mm] = f2bf(acc[st][r]);
        } else {
          const int b = mm / S_GLB, s = mm - b * S_GLB;
          vto[((size_t)b * CC + c) * S_GLB + s] = f2bf(acc[st][r]);
        }
      }
    }
  }
}

// ---------------- window attention, MFMA, keys padded 49->64 (masked)
__global__ __launch_bounds__(256) void win_attn_k(
    const u16* __restrict__ qw, const u16* __restrict__ kw,
    const u16* __restrict__ vtw, u16* __restrict__ aow) {
  __shared__ __align__(16) u16 psh[4][16][72];
  __shared__ float lsh[4][16];
  const int tid = threadIdx.x;
  const int wvi = tid >> 6, lane = tid & 63;
  const int lo = lane & 15, hi = lane >> 4, hi4 = hi * 4;
  const int wh = blockIdx.x * 4 + wvi;
  const int win = wh >> 2, hd = wh & 3;
  const f32x4 zero4 = {0.f, 0.f, 0.f, 0.f};

  bf16x8 kf[4], vf[2][2];
#pragma unroll
  for (int st = 0; st < 4; ++st)
    kf[st] = *reinterpret_cast<const bf16x8*>(&kw[((size_t)wh * 49 + st * 16 + lo) * DK + 8 * hi]);
#pragma unroll
  for (int dst = 0; dst < 2; ++dst)
#pragma unroll
    for (int kch = 0; kch < 2; ++kch)
      vf[dst][kch] = *reinterpret_cast<const bf16x8*>(
          &vtw[(size_t)(hd * DK + dst * 16 + lo) * VTW_STRIDE + win * 49 + kch * 32 + 8 * hi]);

#pragma unroll
  for (int g = 0; g < 4; ++g) {
    const bf16x8 qf = *reinterpret_cast<const bf16x8*>(
        &qw[((size_t)wh * 49 + g * 16 + lo) * DK + 8 * hi]);
    f32x4 s4[4];
#pragma unroll
    for (int st = 0; st < 4; ++st) {
      s4[st] = __builtin_amdgcn_mfma_f32_16x16x32_bf16(kf[st], qf, zero4, 0, 0, 0);
#pragma unroll
      for (int r = 0; r < 4; ++r)
        if (st * 16 + hi4 + r >= 49) s4[st][r] = -1e30f;  // mask pad keys
    }
    float rm = s4[0][0];
#pragma unroll
    for (int st = 0; st < 4; ++st)
#pragma unroll
      for (int r = 0; r < 4; ++r) rm = fmaxf(rm, s4[st][r]);
    rm = fmaxf(rm, __shfl_xor(rm, 16));
    rm = fmaxf(rm, __shfl_xor(rm, 32));
    float psum = 0.f;
#pragma unroll
    for (int st = 0; st < 4; ++st) {
      const float p0 = fexp2(s4[st][0] - rm), p1 = fexp2(s4[st][1] - rm);
      const float p2 = fexp2(s4[st][2] - rm), p3 = fexp2(s4[st][3] - rm);
      psum += (p0 + p1) + (p2 + p3);
      uint2 pk;
      pk.x = pk2bf(p0, p1);
      pk.y = pk2bf(p2, p3);
      *reinterpret_cast<uint2*>(&psh[wvi][lo][st * 16 + hi4]) = pk;
    }
    psum += __shfl_xor(psum, 16);
    psum += __shfl_xor(psum, 32);
    if (hi == 0) lsh[wvi][lo] = 1.0f / psum;
    asm volatile("" ::: "memory");
    f32x4 acc0 = zero4, acc1 = zero4;
#pragma unroll
    for (int kch = 0; kch < 2; ++kch) {
      const bf16x8 pa = *reinterpret_cast<const bf16x8*>(&psh[wvi][lo][kch * 32 + 8 * hi]);
      acc0 = __builtin_amdgcn_mfma_f32_16x16x32_bf16(pa, vf[0][kch], acc0, 0, 0, 0);
      acc1 = __builtin_amdgcn_mfma_f32_16x16x32_bf16(pa, vf[1][kch], acc1, 0, 0, 0);
    }
    const f32x4 rl4 = *reinterpret_cast<const f32x4*>(&lsh[wvi][hi4]);
#pragma unroll
    for (int r = 0; r < 4; ++r) {
      const int qrow = g * 16 + hi4 + r;
      if (qrow < 49) {
        const size_t tw = (size_t)win * 49 + qrow;
        aow[tw * CC + hd * DK + lo] = f2bf(acc0[r] * rl4[r]);
        aow[tw * CC + hd * DK + 16 + lo] = f2bf(acc1[r] * rl4[r]);
      }
    }
  }
}

// ---------------- global flash attention: barrier-free, frags direct from L2
__global__ __launch_bounds__(256) void glb_attn_k(
    const u16* __restrict__ qg, const u16* __restrict__ kg,
    const u16* __restrict__ vtg, u16* __restrict__ aog) {
  __shared__ __align__(16) u16 psh[4][16][72];
  __shared__ float crr[4][16];
  __shared__ float lsh[4][16];
  const int tid = threadIdx.x;
  const int w = tid >> 6, lane = tid & 63;
  const int lo = lane & 15, hi = lane >> 4, hi4 = hi * 4;
  const int bh = blockIdx.y;
  const int q0 = blockIdx.x * 64;
  const f32x4 zero4 = {0.f, 0.f, 0.f, 0.f};

  const bf16x8 qfrag = *reinterpret_cast<const bf16x8*>(
      &qg[((size_t)bh * S_GLB + q0 + w * 16 + lo) * DK + 8 * hi]);
  const u16* kg0 = kg + (size_t)bh * S_GLB * DK;
  const u16* vg0 = vtg + (size_t)bh * DK * S_GLB;

  float m = -1e30f, l = 0.f;
  f32x4 oacc0 = zero4, oacc1 = zero4;
  bf16x8 kfA[4], vfA[4], kfB[4], vfB[4];

  auto loadt = [&](bf16x8 (&kf)[4], bf16x8 (&vf)[4], int kt) {
#pragma unroll
    for (int st = 0; st < 4; ++st)
      kf[st] = *reinterpret_cast<const bf16x8*>(
          &kg0[(size_t)(kt * 64 + st * 16 + lo) * DK + 8 * hi]);
#pragma unroll
    for (int dst = 0; dst < 2; ++dst)
#pragma unroll
      for (int kch = 0; kch < 2; ++kch)
        vf[dst * 2 + kch] = *reinterpret_cast<const bf16x8*>(
            &vg0[(size_t)(dst * 16 + lo) * S_GLB + kt * 64 + kch * 32 + 8 * hi]);
  };

  auto compute = [&](const bf16x8 (&kf)[4], const bf16x8 (&vf)[4]) {
    f32x4 s4[4];
#pragma unroll
    for (int st = 0; st < 4; ++st)
      s4[st] = __builtin_amdgcn_mfma_f32_16x16x32_bf16(kf[st], qfrag, zero4, 0, 0, 0);
    float rm = s4[0][0];
#pragma unroll
    for (int st = 0; st < 4; ++st)
#pragma unroll
      for (int r = 0; r < 4; ++r) rm = fmaxf(rm, s4[st][r]);
    rm = fmaxf(rm, __shfl_xor(rm, 16));
    rm = fmaxf(rm, __shfl_xor(rm, 32));
    if (!__all(rm <= m + 8.0f)) {  // defer-max: skip rescale when growth small
      const float mnew = fmaxf(m, rm);
      const float corr = fexp2(m - mnew);
      m = mnew;
      l *= corr;
      if (hi == 0) crr[w][lo] = corr;
      asm volatile("" ::: "memory");
      const f32x4 c4 = *reinterpret_cast<const f32x4*>(&crr[w][hi4]);
#pragma unroll
      for (int r = 0; r < 4; ++r) { oacc0[r] *= c4[r]; oacc1[r] *= c4[r]; }
    }
    float psum = 0.f;
#pragma unroll
    for (int st = 0; st < 4; ++st) {
      const float p0 = fexp2(s4[st][0] - m), p1 = fexp2(s4[st][1] - m);
      const float p2 = fexp2(s4[st][2] - m), p3 = fexp2(s4[st][3] - m);
      psum += (p0 + p1) + (p2 + p3);
      uint2 pk;
      pk.x = pk2bf(p0, p1);
      pk.y = pk2bf(p2, p3);
      *reinterpret_cast<uint2*>(&psh[w][lo][st * 16 + hi4]) = pk;
    }
    psum += __shfl_xor(psum, 16);
    psum += __shfl_xor(psum, 32);
    l += psum;
    asm volatile("" ::: "memory");
#pragma unroll
    for (int kch = 0; kch < 2; ++kch) {
      const bf16x8 pa = *reinterpret_cast<const bf16x8*>(&psh[w][lo][kch * 32 + 8 * hi]);
      oacc0 = __builtin_amdgcn_mfma_f32_16x16x32_bf16(pa, vf[0 * 2 + kch], oacc0, 0, 0, 0);
      oacc1 = __builtin_amdgcn_mfma_f32_16x16x32_bf16(pa, vf[1 * 2 + kch], oacc1, 0, 0, 0);
    }
  };

  loadt(kfA, vfA, 0);
  for (int kt2 = 0; kt2 < 24; ++kt2) {
    loadt(kfB, vfB, 2 * kt2 + 1);
    compute(kfA, vfA);
    loadt(kfA, vfA, 2 * kt2 + 2);
    compute(kfB, vfB);
  }
  compute(kfA, vfA);  // tile 48

  if (hi == 0) lsh[w][lo] = 1.0f / l;
  asm volatile("" ::: "memory");
  const f32x4 rl4 = *reinterpret_cast<const f32x4*>(&lsh[w][hi4]);
  const int b = bh >> 2, hd = bh & 3;
#pragma unroll
  for (int r = 0; r < 4; ++r) {
    const size_t t = (size_t)b * S_GLB + q0 + w * 16 + hi4 + r;
    aog[t * CC + hd * DK + lo] = f2bf(oacc0[r] * rl4[r]);
    aog[t * CC + hd * DK + 16 + lo] = f2bf(oacc1[r] * rl4[r]);
  }
}

// ---------------- output projection GEMM. MODE 0: window-reverse scatter,
// MODE 1: identity rows + residual (in-place capable).
template <int MODE>
__global__ __launch_bounds__(256) void proj_gemm_k(
    const u16* __restrict__ ain, const u16* __restrict__ wot,
    const float* __restrict__ bo, const float* __restrict__ resid,
    float* __restrict__ xfo) {
  __shared__ __align__(16) u16 xs[64][136];
  __shared__ __align__(16) u16 wt[64][136];
  const int tid = threadIdx.x;
  const int w = tid >> 6, lane = tid & 63;
  const int lo = lane & 15, hi = lane >> 4, hi4 = hi * 4;
  const int m0 = blockIdx.x * 64;
  const int n0 = blockIdx.y * 64;
  {
    const int r = tid >> 2, sg = tid & 3;
    const u16* sx = &ain[(size_t)(m0 + r) * CC + sg * 32];
    const u16* sw = &wot[(size_t)(n0 + r) * CC + sg * 32];
#pragma unroll
    for (int j = 0; j < 4; ++j) {
      *reinterpret_cast<u16x8*>(&xs[r][sg * 32 + j * 8]) = *reinterpret_cast<const u16x8*>(&sx[j * 8]);
      *reinterpret_cast<u16x8*>(&wt[r][sg * 32 + j * 8]) = *reinterpret_cast<const u16x8*>(&sw[j * 8]);
    }
  }
  __syncthreads();
  f32x4 acc[4];
#pragma unroll
  for (int st = 0; st < 4; ++st) {
    const float b_ = bo[n0 + st * 16 + lo];
    acc[st] = (f32x4){b_, b_, b_, b_};
  }
#pragma unroll
  for (int kk = 0; kk < 4; ++kk) {
    const bf16x8 af = *reinterpret_cast<const bf16x8*>(&xs[w * 16 + lo][kk * 32 + 8 * hi]);
#pragma unroll
    for (int st = 0; st < 4; ++st) {
      const bf16x8 bfr = *reinterpret_cast<const bf16x8*>(&wt[st * 16 + lo][kk * 32 + 8 * hi]);
      acc[st] = __builtin_amdgcn_mfma_f32_16x16x32_bf16(af, bfr, acc[st], 0, 0, 0);
    }
  }
#pragma unroll
  for (int r = 0; r < 4; ++r) {
    const int mm = m0 + w * 16 + hi4 + r;
    size_t trow;
    if (MODE == 0) {
      const int win = mm / 49, tok = mm - win * 49;
      const int b = win >> 6, wi = (win >> 3) & 7, wj = win & 7;
      const int ii = tok / 7, jj = tok - ii * 7;
      int hr = wi * 7 + ii + SHIFT; if (hr >= HW) hr -= HW;
      int wr = wj * 7 + jj + SHIFT; if (wr >= HW) wr -= HW;
      trow = ((size_t)b * S_GLB + hr * HW + wr) * CC;
    } else {
      trow = (size_t)mm * CC;
    }
#pragma unroll
    for (int st = 0; st < 4; ++st) {
      const int c = n0 + st * 16 + lo;
      if (MODE == 1)
        xfo[trow + c] = resid[trow + c] + acc[st][r];
      else
        xfo[trow + c] = acc[st][r];
    }
  }
}

// ---------------- LayerNorm fp32 -> bf16
__global__ __launch_bounds__(128) void ln_k(
    const float* __restrict__ xf, const float* __restrict__ g,
    const float* __restrict__ be, u16* __restrict__ ybf) {
  __shared__ float xs[8][CC];
  __shared__ float red[8][2];
  const int t0 = blockIdx.x * 8;
  const int tid = threadIdx.x;
  for (int t2 = 0; t2 < 8; ++t2) xs[t2][tid] = xf[(size_t)(t0 + t2) * CC + tid];
  __syncthreads();
  const int wvi = tid >> 6, lane = tid & 63;
  for (int t2 = wvi * 4; t2 < wvi * 4 + 4; ++t2) {
    const float v0 = xs[t2][lane], v1 = xs[t2][64 + lane];
    float s = v0 + v1, sq = v0 * v0 + v1 * v1;
#pragma unroll
    for (int off = 1; off < 64; off <<= 1) { s += __shfl_xor(s, off); sq += __shfl_xor(sq, off); }
    if (lane == 0) {
      const float mu = s * 0.0078125f;
      const float var = sq * 0.0078125f - mu * mu;
      red[t2][0] = mu; red[t2][1] = rsqrtf(var + 1e-5f);
    }
  }
  __syncthreads();
  const float gg = g[tid], bb = be[tid];
  for (int t2 = 0; t2 < 8; ++t2)
    ybf[(size_t)(t0 + t2) * CC + tid] = f2bf((xs[t2][tid] - red[t2][0]) * red[t2][1] * gg + bb);
}

// ---------------- GEMM1 [NTOK,128]@[128,512] + gelu -> bf16
__global__ __launch_bounds__(256) void gemm1_k(
    const u16* __restrict__ ybf, const u16* __restrict__ w1t,
    const float* __restrict__ b1, u16* __restrict__ hb) {
  __shared__ __align__(16) u16 xs[64][136];
  __shared__ __align__(16) u16 wt[64][136];
  const int tid = threadIdx.x;
  const int w = tid >> 6, lane = tid & 63;
  const int lo = lane & 15, hi = lane >> 4;
  const int m0 = blockIdx.x * 64, n0 = blockIdx.y * 64;
  {
    const int r = tid >> 2, sg = tid & 3;
    const u16* src_x = &ybf[(size_t)(m0 + r) * CC + sg * 32];
    const u16* src_w = &w1t[(size_t)(n0 + r) * CC + sg * 32];
#pragma unroll
    for (int j = 0; j < 4; ++j) {
      *reinterpret_cast<u16x8*>(&xs[r][sg * 32 + j * 8]) = *reinterpret_cast<const u16x8*>(&src_x[j * 8]);
      *reinterpret_cast<u16x8*>(&wt[r][sg * 32 + j * 8]) = *reinterpret_cast<const u16x8*>(&src_w[j * 8]);
    }
  }
  __syncthreads();
  f32x4 acc[4];
#pragma unroll
  for (int st = 0; st < 4; ++st) {
    const float bv = b1[n0 + st * 16 + lo];
    acc[st] = (f32x4){bv, bv, bv, bv};
  }
#pragma unroll
  for (int kk = 0; kk < 4; ++kk) {
    const bf16x8 af = *reinterpret_cast<const bf16x8*>(&xs[w * 16 + lo][kk * 32 + 8 * hi]);
#pragma unroll
    for (int st = 0; st < 4; ++st) {
      const bf16x8 bfr = *reinterpret_cast<const bf16x8*>(&wt[st * 16 + lo][kk * 32 + 8 * hi]);
      acc[st] = __builtin_amdgcn_mfma_f32_16x16x32_bf16(af, bfr, acc[st], 0, 0, 0);
    }
  }
#pragma unroll
  for (int st = 0; st < 4; ++st) {
#pragma unroll
    for (int r = 0; r < 4; ++r) {
      const float val = acc[st][r];
      const float gel = 0.5f * val * (1.0f + erff(val * 0.70710678118f));
      hb[(size_t)(m0 + w * 16 + (hi << 2) + r) * 512 + n0 + st * 16 + lo] = f2bf(gel);
    }
  }
}

// ---------------- GEMM2 [NTOK,512]@[512,128] + residual -> out
__global__ __launch_bounds__(128) void gemm2_k(
    const u16* __restrict__ hb, const u16* __restrict__ w2t,
    const float* __restrict__ b2, const float* __restrict__ xf,
    float* __restrict__ out) {
  __shared__ __align__(16) u16 xs[32][136];
  __shared__ __align__(16) u16 wt[64][136];
  const int tid = threadIdx.x;
  const int w = tid >> 6, lane = tid & 63;
  const int lo = lane & 15, hi = lane >> 4;
  const int m0 = blockIdx.x * 32, n0 = blockIdx.y * 64;
  f32x4 acc[4];
#pragma unroll
  for (int st = 0; st < 4; ++st) {
    const float bv = b2[n0 + st * 16 + lo];
    acc[st] = (f32x4){bv, bv, bv, bv};
  }
  for (int kc = 0; kc < 4; ++kc) {
    __syncthreads();
    {
      const int r = tid >> 2, sg = tid & 3;
      const u16* src_x = &hb[(size_t)(m0 + r) * 512 + kc * 128 + sg * 32];
#pragma unroll
      for (int j = 0; j < 4; ++j)
        *reinterpret_cast<u16x8*>(&xs[r][sg * 32 + j * 8]) = *reinterpret_cast<const u16x8*>(&src_x[j * 8]);
      const int r2 = tid >> 1, sg2 = tid & 1;
      const u16* src_w = &w2t[(size_t)(n0 + r2) * 512 + kc * 128 + sg2 * 64];
#pragma unroll
      for (int j = 0; j < 8; ++j)
        *reinterpret_cast<u16x8*>(&wt[r2][sg2 * 64 + j * 8]) = *reinterpret_cast<const u16x8*>(&src_w[j * 8]);
    }
    __syncthreads();
#pragma unroll
    for (int kk = 0; kk < 4; ++kk) {
      const bf16x8 af = *reinterpret_cast<const bf16x8*>(&xs[w * 16 + lo][kk * 32 + 8 * hi]);
#pragma unroll
      for (int st = 0; st < 4; ++st) {
        const bf16x8 bfr = *reinterpret_cast<const bf16x8*>(&wt[st * 16 + lo][kk * 32 + 8 * hi]);
        acc[st] = __builtin_amdgcn_mfma_f32_16x16x32_bf16(af, bfr, acc[st], 0, 0, 0);
      }
    }
  }
#pragma unroll
  for (int st = 0; st < 4; ++st) {
#pragma unroll
    for (int r = 0; r < 4; ++r) {
      const size_t idx = (size_t)(m0 + w * 16 + (hi << 2) + r) * CC + n0 + st * 16 + lo;
      out[idx] = xf[idx] + acc[st][r];
    }
  }
}

extern "C" void kernel_launch(void* const* d_in, const int* in_sizes, int n_in,
                              void* d_out, int out_size, void* d_ws, size_t ws_size,
                              hipStream_t stream) {
  (void)in_sizes; (void)n_in; (void)out_size; (void)ws_size;
  const float* x   = (const float*)d_in[0];
  const float* wq  = (const float*)d_in[1];
  const float* bq  = (const float*)d_in[2];
  const float* wk  = (const float*)d_in[3];
  const float* bk  = (const float*)d_in[4];
  const float* wv  = (const float*)d_in[5];
  const float* bv  = (const float*)d_in[6];
  const float* wo  = (const float*)d_in[7];
  const float* bo  = (const float*)d_in[8];
  const float* w1  = (const float*)d_in[9];
  const float* b1  = (const float*)d_in[10];
  const float* w2  = (const float*)d_in[11];
  const float* b2  = (const float*)d_in[12];
  const float* g1  = (const float*)d_in[13];
  const float* be1 = (const float*)d_in[14];
  const float* g2  = (const float*)d_in[15];
  const float* be2 = (const float*)d_in[16];
  float* out = (float*)d_out;

  char* p = (char*)d_ws;
  auto alloc = [&](size_t bytes) { char* r = p; p += (bytes + 255) & ~(size_t)255; return r; };
  float* xf  = (float*)alloc((size_t)NTOK * CC * 4);
  u16* xg    = (u16*)alloc((size_t)NTOK * CC * 2);            // also ybf (ln1/ln2 out)
  u16* qw    = (u16*)alloc((size_t)NTOK * CC * 2 + 4096);     // also qg
  u16* kw    = (u16*)alloc((size_t)NTOK * CC * 2 + 4096);     // also kg
  u16* vtw   = (u16*)alloc((size_t)CC * VTW_STRIDE * 2);      // also vtg (512x3136 fits)
  u16* aow   = (u16*)alloc((size_t)NTOK * CC * 2);            // also aog
  u16* hb    = (u16*)alloc((size_t)NTOK * 512 * 2);
  u16* wqkvt = (u16*)alloc(3 * 16384 * 2);
  u16* wot   = (u16*)alloc(16384 * 2);
  u16* w1t   = (u16*)alloc(65536 * 2);
  u16* w2t   = (u16*)alloc(65536 * 2);

  cvt4_k<<<256, 256, 0, stream>>>(wq, wk, wv, wo, wqkvt, wot);
  cvt_w_k<<<256, 256, 0, stream>>>(w1, w1t, CC, 512);
  cvt_w_k<<<256, 256, 0, stream>>>(w2, w2t, 512, CC);

  win_gather_k<<<NTOK / 2, 256, 0, stream>>>(x, xg);
  qkv_gemm_k<0><<<dim3(NTOK / 64, 6), 256, 0, stream>>>(xg, wqkvt, bq, bk, bv, qw, kw, vtw);
  win_attn_k<<<256, 256, 0, stream>>>(qw, kw, vtw, aow);
  proj_gemm_k<0><<<dim3(NTOK / 64, 2), 256, 0, stream>>>(aow, wot, bo, nullptr, xf);

  ln_k<<<NTOK / 8, 128, 0, stream>>>(xf, g1, be1, xg);
  qkv_gemm_k<1><<<dim3(NTOK / 64, 6), 256, 0, stream>>>(xg, wqkvt, bq, bk, bv, qw, kw, vtw);
  glb_attn_k<<<dim3(S_GLB / 64, 16), 256, 0, stream>>>(qw, kw, vtw, aow);
  proj_gemm_k<1><<<dim3(NTOK / 64, 2), 256, 0, stream>>>(aow, wot, bo, xf, xf);

  ln_k<<<NTOK / 8, 128, 0, stream>>>(xf, g2, be2, xg);
  gemm1_k<<<dim3(NTOK / 64, 8), 256, 0, stream>>>(xg, w1t, b1, hb);
  gemm2_k<<<dim3(NTOK / 32, 2), 128, 0, stream>>>(hb, w2t, b2, xf, out);
}

// Round 5
// 135.015 us; speedup vs baseline: 5.4318x; 1.5850x over previous
//
#include <hip/hip_runtime.h>
#include <hip/hip_bf16.h>
#include <math.h>

#define NH 4
#define DK 32
#define CC 128
#define HW 56
#define SHIFT 3
#define NTOK 12544   // 4*56*56 == 256*49
#define S_GLB 3136
#define VTW_STRIDE 12608
#define SCALE_L2E 0.25503488f  // log2(e)/sqrt(32): exp2-domain softmax scale

typedef unsigned short u16;
typedef short bf16x8 __attribute__((ext_vector_type(8)));
typedef unsigned short u16x8 __attribute__((ext_vector_type(8)));
typedef float f32x4 __attribute__((ext_vector_type(4)));

static __device__ __forceinline__ u16 f2bf(float f) {
  unsigned int b = __builtin_bit_cast(unsigned int, f);
  return (u16)((b + 0x7FFFu + ((b >> 16) & 1u)) >> 16);
}
static __device__ __forceinline__ unsigned pk2bf(float a, float b) {
  unsigned r;
  asm("v_cvt_pk_bf16_f32 %0, %1, %2" : "=v"(r) : "v"(a), "v"(b));
  return r;
}
static __device__ __forceinline__ float fexp2(float x) {
  float r;
  asm("v_exp_f32 %0, %1" : "=v"(r) : "v"(x));
  return r;
}

// ---------------- all weight converts in one kernel (196608 elements)
__global__ __launch_bounds__(256) void cvt_all_k(
    const float* __restrict__ w1, const float* __restrict__ w2,
    const float* __restrict__ wq, const float* __restrict__ wk,
    const float* __restrict__ wv, const float* __restrict__ wo,
    u16* __restrict__ w1t, u16* __restrict__ w2t,
    u16* __restrict__ wqkvt, u16* __restrict__ wot) {
  const int idx = blockIdx.x * 256 + threadIdx.x;
  if (idx < 65536) {            // w1 [128][512] -> w1t [512][128]
    const int c = idx >> 7, r = idx & 127;
    w1t[idx] = f2bf(w1[r * 512 + c]);
  } else if (idx < 131072) {    // w2 [512][128] -> w2t [128][512]
    const int o = idx - 65536;
    const int c = o / 512, r = o - c * 512;
    w2t[o] = f2bf(w2[r * 128 + c]);
  } else {                      // four 128x128 -> transposed
    const int o = idx - 131072;
    const int which = o >> 14, oo = o & 16383;
    const int c = oo >> 7, r = oo & 127;
    const float* src = (which == 0) ? wq : (which == 1) ? wk : (which == 2) ? wv : wo;
    u16* dst = (which < 3) ? (wqkvt + which * 16384) : wot;
    dst[oo] = f2bf(src[r * 128 + c]);
  }
}

// ---------------- shift + window-partition gather -> bf16 [t_w][128]
__global__ __launch_bounds__(256) void win_gather_k(
    const float* __restrict__ x, u16* __restrict__ xg) {
  const int t = blockIdx.x * 2 + (threadIdx.x >> 7);
  const int c = threadIdx.x & 127;
  const int win = t / 49, tok = t % 49;
  const int b = win >> 6, wrem = win & 63;
  const int wi = wrem >> 3, wj = wrem & 7;
  const int i = tok / 7, j = tok % 7;
  int hh = wi * 7 + i + SHIFT; if (hh >= HW) hh -= HW;
  int ww = wj * 7 + j + SHIFT; if (ww >= HW) ww -= HW;
  xg[(size_t)t * CC + c] = f2bf(x[((size_t)(b * HW + hh) * HW + ww) * CC + c]);
}

// ---------------- fused QKV GEMM. PATH 0: window layout, PATH 1: global layout.
template <int PATH>
__global__ __launch_bounds__(256) void qkv_gemm_k(
    const u16* __restrict__ xin, const u16* __restrict__ wqkvt,
    const float* __restrict__ bq, const float* __restrict__ bk,
    const float* __restrict__ bv,
    u16* __restrict__ qo, u16* __restrict__ ko, u16* __restrict__ vto) {
  __shared__ __align__(16) u16 xs[64][136];
  __shared__ __align__(16) u16 wt[64][136];
  const int tid = threadIdx.x;
  const int w = tid >> 6, lane = tid & 63;
  const int lo = lane & 15, hi = lane >> 4, hi4 = hi * 4;
  const int m0 = blockIdx.x * 64;
  const int widx = blockIdx.y >> 1;
  const int n0 = (blockIdx.y & 1) * 64;
  {
    const int r = tid >> 2, sg = tid & 3;
    const u16* sx = &xin[(size_t)(m0 + r) * CC + sg * 32];
    const u16* sw = &wqkvt[(size_t)widx * CC * CC + (size_t)(n0 + r) * CC + sg * 32];
#pragma unroll
    for (int j = 0; j < 4; ++j) {
      *reinterpret_cast<u16x8*>(&xs[r][sg * 32 + j * 8]) = *reinterpret_cast<const u16x8*>(&sx[j * 8]);
      *reinterpret_cast<u16x8*>(&wt[r][sg * 32 + j * 8]) = *reinterpret_cast<const u16x8*>(&sw[j * 8]);
    }
  }
  __syncthreads();
  if (widx < 2) {
    const float* bias = (widx == 0) ? bq : bk;
    u16* outp = (widx == 0) ? qo : ko;
    const float oscale = (widx == 0) ? SCALE_L2E : 1.0f;
    f32x4 acc[4];
#pragma unroll
    for (int st = 0; st < 4; ++st) {
      const float b_ = bias[n0 + st * 16 + lo];
      acc[st] = (f32x4){b_, b_, b_, b_};
    }
#pragma unroll
    for (int kk = 0; kk < 4; ++kk) {
      const bf16x8 af = *reinterpret_cast<const bf16x8*>(&xs[w * 16 + lo][kk * 32 + 8 * hi]);
#pragma unroll
      for (int st = 0; st < 4; ++st) {
        const bf16x8 bfr = *reinterpret_cast<const bf16x8*>(&wt[st * 16 + lo][kk * 32 + 8 * hi]);
        acc[st] = __builtin_amdgcn_mfma_f32_16x16x32_bf16(af, bfr, acc[st], 0, 0, 0);
      }
    }
#pragma unroll
    for (int r = 0; r < 4; ++r) {
      const int mm = m0 + w * 16 + hi4 + r;
      size_t rowbase, hstride;
      if (PATH == 0) {
        const int win = mm / 49, tok = mm - win * 49;
        rowbase = ((size_t)(win * 4) * 49 + tok) * DK;
        hstride = (size_t)49 * DK;
      } else {
        const int b = mm / S_GLB, s = mm - b * S_GLB;
        rowbase = ((size_t)(b * 4) * S_GLB + s) * DK;
        hstride = (size_t)S_GLB * DK;
      }
#pragma unroll
      for (int st = 0; st < 4; ++st) {
        const int c = n0 + st * 16 + lo, h = c >> 5, d = c & 31;
        outp[rowbase + (size_t)h * hstride + d] = f2bf(acc[st][r] * oscale);
      }
    }
  } else {
    f32x4 bias4;
#pragma unroll
    for (int r = 0; r < 4; ++r) bias4[r] = bv[n0 + w * 16 + hi4 + r];
    f32x4 acc[4];
#pragma unroll
    for (int st = 0; st < 4; ++st) acc[st] = bias4;
#pragma unroll
    for (int kk = 0; kk < 4; ++kk) {
      const bf16x8 af = *reinterpret_cast<const bf16x8*>(&wt[w * 16 + lo][kk * 32 + 8 * hi]);
#pragma unroll
      for (int st = 0; st < 4; ++st) {
        const bf16x8 bfr = *reinterpret_cast<const bf16x8*>(&xs[st * 16 + lo][kk * 32 + 8 * hi]);
        acc[st] = __builtin_amdgcn_mfma_f32_16x16x32_bf16(af, bfr, acc[st], 0, 0, 0);
      }
    }
#pragma unroll
    for (int st = 0; st < 4; ++st) {
      const int mm = m0 + st * 16 + lo;
#pragma unroll
      for (int r = 0; r < 4; ++r) {
        const int c = n0 + w * 16 + hi4 + r;
        if (PATH == 0) {
          vto[(size_t)c * VTW_STRIDE + mm] = f2bf(acc[st][r]);
        } else {
          const int b = mm / S_GLB, s = mm - b * S_GLB;
          vto[((size_t)b * CC + c) * S_GLB + s] = f2bf(acc[st][r]);
        }
      }
    }
  }
}

// ---------------- window attention: no-max exp2 softmax, l via ones-MFMA
__global__ __launch_bounds__(256) void win_attn_k(
    const u16* __restrict__ qw, const u16* __restrict__ kw,
    const u16* __restrict__ vtw, u16* __restrict__ aow) {
  __shared__ __align__(16) u16 psh[4][16][72];
  const int tid = threadIdx.x;
  const int wvi = tid >> 6, lane = tid & 63;
  const int lo = lane & 15, hi = lane >> 4, hi4 = hi * 4;
  const int wh = blockIdx.x * 4 + wvi;
  const int win = wh >> 2, hd = wh & 3;
  const f32x4 zero4 = {0.f, 0.f, 0.f, 0.f};
  bf16x8 ones;
#pragma unroll
  for (int j = 0; j < 8; ++j) ones[j] = (short)0x3F80;

  bf16x8 kf[4], vf[2][2];
#pragma unroll
  for (int st = 0; st < 4; ++st)
    kf[st] = *reinterpret_cast<const bf16x8*>(&kw[((size_t)wh * 49 + st * 16 + lo) * DK + 8 * hi]);
#pragma unroll
  for (int dst = 0; dst < 2; ++dst)
#pragma unroll
    for (int kch = 0; kch < 2; ++kch)
      vf[dst][kch] = *reinterpret_cast<const bf16x8*>(
          &vtw[(size_t)(hd * DK + dst * 16 + lo) * VTW_STRIDE + win * 49 + kch * 32 + 8 * hi]);

#pragma unroll
  for (int g = 0; g < 4; ++g) {
    const bf16x8 qf = *reinterpret_cast<const bf16x8*>(
        &qw[((size_t)wh * 49 + g * 16 + lo) * DK + 8 * hi]);
    f32x4 s4[4];
#pragma unroll
    for (int st = 0; st < 4; ++st) {
      s4[st] = __builtin_amdgcn_mfma_f32_16x16x32_bf16(kf[st], qf, zero4, 0, 0, 0);
#pragma unroll
      for (int r = 0; r < 4; ++r)
        if (st * 16 + hi4 + r >= 49) s4[st][r] = -1e30f;  // mask pad keys -> p=0
    }
#pragma unroll
    for (int st = 0; st < 4; ++st) {
      uint2 pk;
      pk.x = pk2bf(fexp2(s4[st][0]), fexp2(s4[st][1]));
      pk.y = pk2bf(fexp2(s4[st][2]), fexp2(s4[st][3]));
      *reinterpret_cast<uint2*>(&psh[wvi][lo][st * 16 + hi4]) = pk;
    }
    asm volatile("" ::: "memory");
    f32x4 acc0 = zero4, acc1 = zero4, lacc = zero4;
#pragma unroll
    for (int kch = 0; kch < 2; ++kch) {
      const bf16x8 pa = *reinterpret_cast<const bf16x8*>(&psh[wvi][lo][kch * 32 + 8 * hi]);
      acc0 = __builtin_amdgcn_mfma_f32_16x16x32_bf16(pa, vf[0][kch], acc0, 0, 0, 0);
      acc1 = __builtin_amdgcn_mfma_f32_16x16x32_bf16(pa, vf[1][kch], acc1, 0, 0, 0);
      lacc = __builtin_amdgcn_mfma_f32_16x16x32_bf16(pa, ones, lacc, 0, 0, 0);
    }
#pragma unroll
    for (int r = 0; r < 4; ++r) {
      const int qrow = g * 16 + hi4 + r;
      if (qrow < 49) {
        const float rl = 1.0f / lacc[r];
        const size_t tw = (size_t)win * 49 + qrow;
        aow[tw * CC + hd * DK + lo] = f2bf(acc0[r] * rl);
        aow[tw * CC + hd * DK + 16 + lo] = f2bf(acc1[r] * rl);
      }
    }
  }
}

// ---------------- global attention: LDS-staged dbuf, no-max exp2, l via ones-MFMA
__global__ __launch_bounds__(256) void glb_attn_k(
    const u16* __restrict__ qg, const u16* __restrict__ kg,
    const u16* __restrict__ vtg, u16* __restrict__ aog) {
  __shared__ __align__(16) u16 ksh[2][64][40];
  __shared__ __align__(16) u16 vtsh[2][32][72];
  __shared__ __align__(16) u16 psh[4][16][72];
  const int tid = threadIdx.x;
  const int w = tid >> 6, lane = tid & 63;
  const int lo = lane & 15, hi = lane >> 4, hi4 = hi * 4;
  const int bh = blockIdx.y;
  const int q0 = blockIdx.x * 64;
  const f32x4 zero4 = {0.f, 0.f, 0.f, 0.f};
  bf16x8 ones;
#pragma unroll
  for (int j = 0; j < 8; ++j) ones[j] = (short)0x3F80;

  const bf16x8 qfrag = *reinterpret_cast<const bf16x8*>(
      &qg[((size_t)bh * S_GLB + q0 + w * 16 + lo) * DK + 8 * hi]);
  const u16* kg0 = kg + (size_t)bh * S_GLB * DK;
  const u16* vg0 = vtg + (size_t)bh * DK * S_GLB;

  f32x4 oacc0 = zero4, oacc1 = zero4, lacc = zero4;

  const int krow = tid >> 2, kc = tid & 3;   // 64 rows x 4 chunks of 8 u16
  const int vrow = tid >> 3, vc = tid & 7;   // 32 rows x 8 chunks of 8 u16

  // prologue: stage tile 0 into buf 0
  *reinterpret_cast<u16x8*>(&ksh[0][krow][kc * 8]) =
      *reinterpret_cast<const u16x8*>(&kg0[(size_t)krow * DK + kc * 8]);
  *reinterpret_cast<u16x8*>(&vtsh[0][vrow][vc * 8]) =
      *reinterpret_cast<const u16x8*>(&vg0[(size_t)vrow * S_GLB + vc * 8]);
  __syncthreads();

  for (int kt = 0; kt < 49; ++kt) {
    const int cur = kt & 1, nxt = cur ^ 1;
    u16x8 knext, vnext;
    const bool have = (kt + 1) < 49;
    if (have) {   // issue next-tile loads early; write after compute (T14)
      knext = *reinterpret_cast<const u16x8*>(
          &kg0[(size_t)((kt + 1) * 64 + krow) * DK + kc * 8]);
      vnext = *reinterpret_cast<const u16x8*>(
          &vg0[(size_t)vrow * S_GLB + (kt + 1) * 64 + vc * 8]);
    }
    // S^T = K*Q^T
    f32x4 s4[4];
#pragma unroll
    for (int st = 0; st < 4; ++st) {
      const bf16x8 kfrag = *reinterpret_cast<const bf16x8*>(&ksh[cur][st * 16 + lo][8 * hi]);
      s4[st] = __builtin_amdgcn_mfma_f32_16x16x32_bf16(kfrag, qfrag, zero4, 0, 0, 0);
    }
    // p = exp2(s)  (no max subtraction: scores bounded, fp32/bf16 safe)
#pragma unroll
    for (int st = 0; st < 4; ++st) {
      uint2 pk;
      pk.x = pk2bf(fexp2(s4[st][0]), fexp2(s4[st][1]));
      pk.y = pk2bf(fexp2(s4[st][2]), fexp2(s4[st][3]));
      *reinterpret_cast<uint2*>(&psh[w][lo][st * 16 + hi4]) = pk;
    }
    asm volatile("" ::: "memory");
    // PV + l accumulation
#pragma unroll
    for (int kch = 0; kch < 2; ++kch) {
      const bf16x8 pa = *reinterpret_cast<const bf16x8*>(&psh[w][lo][kch * 32 + 8 * hi]);
      const bf16x8 v0 = *reinterpret_cast<const bf16x8*>(&vtsh[cur][lo][kch * 32 + 8 * hi]);
      const bf16x8 v1 = *reinterpret_cast<const bf16x8*>(&vtsh[cur][16 + lo][kch * 32 + 8 * hi]);
      oacc0 = __builtin_amdgcn_mfma_f32_16x16x32_bf16(pa, v0, oacc0, 0, 0, 0);
      oacc1 = __builtin_amdgcn_mfma_f32_16x16x32_bf16(pa, v1, oacc1, 0, 0, 0);
      lacc = __builtin_amdgcn_mfma_f32_16x16x32_bf16(pa, ones, lacc, 0, 0, 0);
    }
    if (have) {
      *reinterpret_cast<u16x8*>(&ksh[nxt][krow][kc * 8]) = knext;
      *reinterpret_cast<u16x8*>(&vtsh[nxt][vrow][vc * 8]) = vnext;
    }
    __syncthreads();
  }

  const int b = bh >> 2, hd = bh & 3;
#pragma unroll
  for (int r = 0; r < 4; ++r) {
    const float rl = 1.0f / lacc[r];
    const size_t t = (size_t)b * S_GLB + q0 + w * 16 + hi4 + r;
    aog[t * CC + hd * DK + lo] = f2bf(oacc0[r] * rl);
    aog[t * CC + hd * DK + 16 + lo] = f2bf(oacc1[r] * rl);
  }
}

// ---------------- output projection GEMM. MODE 0: window-reverse scatter,
// MODE 1: identity rows + residual.
template <int MODE>
__global__ __launch_bounds__(256) void proj_gemm_k(
    const u16* __restrict__ ain, const u16* __restrict__ wot,
    const float* __restrict__ bo, const float* __restrict__ resid,
    float* __restrict__ xfo) {
  __shared__ __align__(16) u16 xs[64][136];
  __shared__ __align__(16) u16 wt[64][136];
  const int tid = threadIdx.x;
  const int w = tid >> 6, lane = tid & 63;
  const int lo = lane & 15, hi = lane >> 4, hi4 = hi * 4;
  const int m0 = blockIdx.x * 64;
  const int n0 = blockIdx.y * 64;
  {
    const int r = tid >> 2, sg = tid & 3;
    const u16* sx = &ain[(size_t)(m0 + r) * CC + sg * 32];
    const u16* sw = &wot[(size_t)(n0 + r) * CC + sg * 32];
#pragma unroll
    for (int j = 0; j < 4; ++j) {
      *reinterpret_cast<u16x8*>(&xs[r][sg * 32 + j * 8]) = *reinterpret_cast<const u16x8*>(&sx[j * 8]);
      *reinterpret_cast<u16x8*>(&wt[r][sg * 32 + j * 8]) = *reinterpret_cast<const u16x8*>(&sw[j * 8]);
    }
  }
  __syncthreads();
  f32x4 acc[4];
#pragma unroll
  for (int st = 0; st < 4; ++st) {
    const float b_ = bo[n0 + st * 16 + lo];
    acc[st] = (f32x4){b_, b_, b_, b_};
  }
#pragma unroll
  for (int kk = 0; kk < 4; ++kk) {
    const bf16x8 af = *reinterpret_cast<const bf16x8*>(&xs[w * 16 + lo][kk * 32 + 8 * hi]);
#pragma unroll
    for (int st = 0; st < 4; ++st) {
      const bf16x8 bfr = *reinterpret_cast<const bf16x8*>(&wt[st * 16 + lo][kk * 32 + 8 * hi]);
      acc[st] = __builtin_amdgcn_mfma_f32_16x16x32_bf16(af, bfr, acc[st], 0, 0, 0);
    }
  }
#pragma unroll
  for (int r = 0; r < 4; ++r) {
    const int mm = m0 + w * 16 + hi4 + r;
    size_t trow;
    if (MODE == 0) {
      const int win = mm / 49, tok = mm - win * 49;
      const int b = win >> 6, wi = (win >> 3) & 7, wj = win & 7;
      const int ii = tok / 7, jj = tok - ii * 7;
      int hr = wi * 7 + ii + SHIFT; if (hr >= HW) hr -= HW;
      int wr = wj * 7 + jj + SHIFT; if (wr >= HW) wr -= HW;
      trow = ((size_t)b * S_GLB + hr * HW + wr) * CC;
    } else {
      trow = (size_t)mm * CC;
    }
#pragma unroll
    for (int st = 0; st < 4; ++st) {
      const int c = n0 + st * 16 + lo;
      if (MODE == 1)
        xfo[trow + c] = resid[trow + c] + acc[st][r];
      else
        xfo[trow + c] = acc[st][r];
    }
  }
}

// ---------------- LayerNorm fp32 -> bf16
__global__ __launch_bounds__(128) void ln_k(
    const float* __restrict__ xf, const float* __restrict__ g,
    const float* __restrict__ be, u16* __restrict__ ybf) {
  __shared__ float xs[8][CC];
  __shared__ float red[8][2];
  const int t0 = blockIdx.x * 8;
  const int tid = threadIdx.x;
  for (int t2 = 0; t2 < 8; ++t2) xs[t2][tid] = xf[(size_t)(t0 + t2) * CC + tid];
  __syncthreads();
  const int wvi = tid >> 6, lane = tid & 63;
  for (int t2 = wvi * 4; t2 < wvi * 4 + 4; ++t2) {
    const float v0 = xs[t2][lane], v1 = xs[t2][64 + lane];
    float s = v0 + v1, sq = v0 * v0 + v1 * v1;
#pragma unroll
    for (int off = 1; off < 64; off <<= 1) { s += __shfl_xor(s, off); sq += __shfl_xor(sq, off); }
    if (lane == 0) {
      const float mu = s * 0.0078125f;
      const float var = sq * 0.0078125f - mu * mu;
      red[t2][0] = mu; red[t2][1] = rsqrtf(var + 1e-5f);
    }
  }
  __syncthreads();
  const float gg = g[tid], bb = be[tid];
  for (int t2 = 0; t2 < 8; ++t2)
    ybf[(size_t)(t0 + t2) * CC + tid] = f2bf((xs[t2][tid] - red[t2][0]) * red[t2][1] * gg + bb);
}

// ---------------- GEMM1 [NTOK,128]@[128,512] + gelu -> bf16
__global__ __launch_bounds__(256) void gemm1_k(
    const u16* __restrict__ ybf, const u16* __restrict__ w1t,
    const float* __restrict__ b1, u16* __restrict__ hb) {
  __shared__ __align__(16) u16 xs[64][136];
  __shared__ __align__(16) u16 wt[64][136];
  const int tid = threadIdx.x;
  const int w = tid >> 6, lane = tid & 63;
  const int lo = lane & 15, hi = lane >> 4;
  const int m0 = blockIdx.x * 64, n0 = blockIdx.y * 64;
  {
    const int r = tid >> 2, sg = tid & 3;
    const u16* src_x = &ybf[(size_t)(m0 + r) * CC + sg * 32];
    const u16* src_w = &w1t[(size_t)(n0 + r) * CC + sg * 32];
#pragma unroll
    for (int j = 0; j < 4; ++j) {
      *reinterpret_cast<u16x8*>(&xs[r][sg * 32 + j * 8]) = *reinterpret_cast<const u16x8*>(&src_x[j * 8]);
      *reinterpret_cast<u16x8*>(&wt[r][sg * 32 + j * 8]) = *reinterpret_cast<const u16x8*>(&src_w[j * 8]);
    }
  }
  __syncthreads();
  f32x4 acc[4];
#pragma unroll
  for (int st = 0; st < 4; ++st) {
    const float bv = b1[n0 + st * 16 + lo];
    acc[st] = (f32x4){bv, bv, bv, bv};
  }
#pragma unroll
  for (int kk = 0; kk < 4; ++kk) {
    const bf16x8 af = *reinterpret_cast<const bf16x8*>(&xs[w * 16 + lo][kk * 32 + 8 * hi]);
#pragma unroll
    for (int st = 0; st < 4; ++st) {
      const bf16x8 bfr = *reinterpret_cast<const bf16x8*>(&wt[st * 16 + lo][kk * 32 + 8 * hi]);
      acc[st] = __builtin_amdgcn_mfma_f32_16x16x32_bf16(af, bfr, acc[st], 0, 0, 0);
    }
  }
#pragma unroll
  for (int st = 0; st < 4; ++st) {
#pragma unroll
    for (int r = 0; r < 4; ++r) {
      const float val = acc[st][r];
      const float gel = 0.5f * val * (1.0f + erff(val * 0.70710678118f));
      hb[(size_t)(m0 + w * 16 + (hi << 2) + r) * 512 + n0 + st * 16 + lo] = f2bf(gel);
    }
  }
}

// ---------------- GEMM2 [NTOK,512]@[512,128] + residual -> out (256 threads)
__global__ __launch_bounds__(256) void gemm2_k(
    const u16* __restrict__ hb, const u16* __restrict__ w2t,
    const float* __restrict__ b2, const float* __restrict__ xf,
    float* __restrict__ out) {
  __shared__ __align__(16) u16 xs[64][136];
  __shared__ __align__(16) u16 wt[64][136];
  const int tid = threadIdx.x;
  const int w = tid >> 6, lane = tid & 63;
  const int lo = lane & 15, hi = lane >> 4;
  const int m0 = blockIdx.x * 64, n0 = blockIdx.y * 64;
  f32x4 acc[4];
#pragma unroll
  for (int st = 0; st < 4; ++st) {
    const float bv = b2[n0 + st * 16 + lo];
    acc[st] = (f32x4){bv, bv, bv, bv};
  }
  for (int kc = 0; kc < 4; ++kc) {
    if (kc) __syncthreads();
    {
      const int r = tid >> 2, sg = tid & 3;
      const u16* src_x = &hb[(size_t)(m0 + r) * 512 + kc * 128 + sg * 32];
      const u16* src_w = &w2t[(size_t)(n0 + r) * 512 + kc * 128 + sg * 32];
#pragma unroll
      for (int j = 0; j < 4; ++j) {
        *reinterpret_cast<u16x8*>(&xs[r][sg * 32 + j * 8]) = *reinterpret_cast<const u16x8*>(&src_x[j * 8]);
        *reinterpret_cast<u16x8*>(&wt[r][sg * 32 + j * 8]) = *reinterpret_cast<const u16x8*>(&src_w[j * 8]);
      }
    }
    __syncthreads();
#pragma unroll
    for (int kk = 0; kk < 4; ++kk) {
      const bf16x8 af = *reinterpret_cast<const bf16x8*>(&xs[w * 16 + lo][kk * 32 + 8 * hi]);
#pragma unroll
      for (int st = 0; st < 4; ++st) {
        const bf16x8 bfr = *reinterpret_cast<const bf16x8*>(&wt[st * 16 + lo][kk * 32 + 8 * hi]);
        acc[st] = __builtin_amdgcn_mfma_f32_16x16x32_bf16(af, bfr, acc[st], 0, 0, 0);
      }
    }
  }
#pragma unroll
  for (int st = 0; st < 4; ++st) {
#pragma unroll
    for (int r = 0; r < 4; ++r) {
      const size_t idx = (size_t)(m0 + w * 16 + (hi << 2) + r) * CC + n0 + st * 16 + lo;
      out[idx] = xf[idx] + acc[st][r];
    }
  }
}

extern "C" void kernel_launch(void* const* d_in, const int* in_sizes, int n_in,
                              void* d_out, int out_size, void* d_ws, size_t ws_size,
                              hipStream_t stream) {
  (void)in_sizes; (void)n_in; (void)out_size; (void)ws_size;
  const float* x   = (const float*)d_in[0];
  const float* wq  = (const float*)d_in[1];
  const float* bq  = (const float*)d_in[2];
  const float* wk  = (const float*)d_in[3];
  const float* bk  = (const float*)d_in[4];
  const float* wv  = (const float*)d_in[5];
  const float* bv  = (const float*)d_in[6];
  const float* wo  = (const float*)d_in[7];
  const float* bo  = (const float*)d_in[8];
  const float* w1  = (const float*)d_in[9];
  const float* b1  = (const float*)d_in[10];
  const float* w2  = (const float*)d_in[11];
  const float* b2  = (const float*)d_in[12];
  const float* g1  = (const float*)d_in[13];
  const float* be1 = (const float*)d_in[14];
  const float* g2  = (const float*)d_in[15];
  const float* be2 = (const float*)d_in[16];
  float* out = (float*)d_out;

  char* p = (char*)d_ws;
  auto alloc = [&](size_t bytes) { char* r = p; p += (bytes + 255) & ~(size_t)255; return r; };
  float* xf  = (float*)alloc((size_t)NTOK * CC * 4);
  u16* xg    = (u16*)alloc((size_t)NTOK * CC * 2);            // also ybf (ln1/ln2 out)
  u16* qw    = (u16*)alloc((size_t)NTOK * CC * 2 + 4096);     // also qg
  u16* kw    = (u16*)alloc((size_t)NTOK * CC * 2 + 4096);     // also kg
  u16* vtw   = (u16*)alloc((size_t)CC * VTW_STRIDE * 2);      // also vtg
  u16* aow   = (u16*)alloc((size_t)NTOK * CC * 2);            // also aog
  u16* hb    = (u16*)alloc((size_t)NTOK * 512 * 2);
  u16* wqkvt = (u16*)alloc(3 * 16384 * 2);
  u16* wot   = (u16*)alloc(16384 * 2);
  u16* w1t   = (u16*)alloc(65536 * 2);
  u16* w2t   = (u16*)alloc(65536 * 2);

  cvt_all_k<<<768, 256, 0, stream>>>(w1, w2, wq, wk, wv, wo, w1t, w2t, wqkvt, wot);

  win_gather_k<<<NTOK / 2, 256, 0, stream>>>(x, xg);
  qkv_gemm_k<0><<<dim3(NTOK / 64, 6), 256, 0, stream>>>(xg, wqkvt, bq, bk, bv, qw, kw, vtw);
  win_attn_k<<<256, 256, 0, stream>>>(qw, kw, vtw, aow);
  proj_gemm_k<0><<<dim3(NTOK / 64, 2), 256, 0, stream>>>(aow, wot, bo, nullptr, xf);

  ln_k<<<NTOK / 8, 128, 0, stream>>>(xf, g1, be1, xg);
  qkv_gemm_k<1><<<dim3(NTOK / 64, 6), 256, 0, stream>>>(xg, wqkvt, bq, bk, bv, qw, kw, vtw);
  glb_attn_k<<<dim3(S_GLB / 64, 16), 256, 0, stream>>>(qw, kw, vtw, aow);
  proj_gemm_k<1><<<dim3(NTOK / 64, 2), 256, 0, stream>>>(aow, wot, bo, xf, xf);

  ln_k<<<NTOK / 8, 128, 0, stream>>>(xf, g2, be2, xg);
  gemm1_k<<<dim3(NTOK / 64, 8), 256, 0, stream>>>(xg, w1t, b1, hb);
  gemm2_k<<<dim3(NTOK / 64, 2), 256, 0, stream>>>(hb, w2t, b2, xf, out);
}